// Round 4
// baseline (602.139 us; speedup 1.0000x reference)
//
#include <hip/hip_runtime.h>
#include <hip/hip_bf16.h>

#define HID 128
#define NRBF 20
#define KNN 16
#define NNODE 4096
#define NBATCH 8

typedef __attribute__((ext_vector_type(8))) short short8;
typedef __attribute__((ext_vector_type(4))) float f32x4;

__device__ __forceinline__ short f2bf(float x) {
  __hip_bfloat16 b = __float2bfloat16(x);   // RNE
  return __builtin_bit_cast(short, b);
}
__device__ __forceinline__ float silu_f(float x) {
  // x * rcp(1+e^-x); v_rcp_f32 (~1ulp) instead of precise-div Newton chain —
  // error ~1e-7 relative, invisible under bf16 (7e-3) rounding.
  return x * __builtin_amdgcn_rcpf(1.0f + __expf(-x));
}
// convert 8 consecutive f32 -> short8 of bf16
__device__ __forceinline__ short8 cv8(const float* p) {
  f32x4 a = *(const f32x4*)p;
  f32x4 b = *(const f32x4*)(p + 4);
  short8 r;
  r[0]=f2bf(a[0]); r[1]=f2bf(a[1]); r[2]=f2bf(a[2]); r[3]=f2bf(a[3]);
  r[4]=f2bf(b[0]); r[5]=f2bf(b[1]); r[6]=f2bf(b[2]); r[7]=f2bf(b[3]);
  return r;
}

// ---------------------------------------------------------------------------
// Kernel 1: exact kNN (top-16, stable index tiebreak), f32
// one wave per node; threshold = 16th smallest of per-lane strip minima.
// posL staged as float4 -> single ds_read_b128 per candidate (was 3x b32).
// ---------------------------------------------------------------------------
__global__ __launch_bounds__(512)
void knn_kernel(const float* __restrict__ pos,
                int* __restrict__ eidx, float* __restrict__ edist)
{
  __shared__ f32x4 posL4[NNODE];     // 64 KB
  __shared__ float d2b[8][128];
  __shared__ int   jb[8][128];
  __shared__ int   cntL[8];

  const int tid  = threadIdx.x;
  const int wv   = tid >> 6;
  const int lane = tid & 63;
  const int b    = blockIdx.x >> 7;     // 128 blocks per batch
  const int grp  = blockIdx.x & 127;

  const float* pb = pos + (size_t)b * NNODE * 3;
  for (int idx = tid; idx < NNODE; idx += 512) {
    f32x4 v; v[0] = pb[idx*3]; v[1] = pb[idx*3+1]; v[2] = pb[idx*3+2]; v[3] = 0.f;
    posL4[idx] = v;
  }
  __syncthreads();

  for (int itn = 0; itn < 4; ++itn) {
    const int i = grp * 32 + wv * 4 + itn;
    const f32x4 pi = posL4[i];
    const float pix = pi[0], piy = pi[1], piz = pi[2];

    // pass 1: per-lane strip minima (numpy-exact f32 arithmetic, no FMA)
    float vmin = 3.0e38f;
    for (int t = 0; t < 64; ++t) {
      const int j = t * 64 + lane;
      f32x4 p = posL4[j];
      float dx = __fsub_rn(pix, p[0]);
      float dy = __fsub_rn(piy, p[1]);
      float dz = __fsub_rn(piz, p[2]);
      float d2 = __fadd_rn(__fadd_rn(__fmul_rn(dx,dx), __fmul_rn(dy,dy)), __fmul_rn(dz,dz));
      if (j == i) d2 = 3.0e38f;
      vmin = fminf(vmin, d2);
    }

    // bitonic sort the 64 lane minima (ascending); T = element 15
    float v = vmin;
    #pragma unroll
    for (int k = 2; k <= 64; k <<= 1) {
      #pragma unroll
      for (int jj = k >> 1; jj > 0; jj >>= 1) {
        float o = __shfl_xor(v, jj);
        const bool up   = ((lane & k) == 0);
        const bool lowl = ((lane & jj) == 0);
        float mn = fminf(v, o), mx = fmaxf(v, o);
        v = (up == lowl) ? mn : mx;
      }
    }
    const float T = __shfl(v, 15);   // >= true 16th smallest

    if (lane == 0) cntL[wv] = 0;
    // pass 2: compact candidates with d2 <= T (expected ~20-40)
    for (int t = 0; t < 64; ++t) {
      const int j = t * 64 + lane;
      f32x4 p = posL4[j];
      float dx = __fsub_rn(pix, p[0]);
      float dy = __fsub_rn(piy, p[1]);
      float dz = __fsub_rn(piz, p[2]);
      float d2 = __fadd_rn(__fadd_rn(__fmul_rn(dx,dx), __fmul_rn(dy,dy)), __fmul_rn(dz,dz));
      bool ok = (j != i) && (d2 <= T);
      if (ok) {
        int p2 = atomicAdd(&cntL[wv], 1);
        if (p2 < 128) { d2b[wv][p2] = d2; jb[wv][p2] = j; }
      }
    }
    int cnt = cntL[wv];
    if (cnt > 128) cnt = 128;

    // exact stable rank selection (ties -> lower index, matches top_k)
    for (int s = lane; s < cnt; s += 64) {
      float dm = d2b[wv][s]; int jm = jb[wv][s];
      int rank = 0;
      for (int c = 0; c < cnt; ++c) {
        float dc = d2b[wv][c]; int jc = jb[wv][c];
        if (dc < dm || (dc == dm && jc < jm)) ++rank;
      }
      if (rank < KNN) {
        size_t base = ((size_t)b * NNODE + i) * KNN;
        eidx[base + rank]  = b * NNODE + jm;          // global row index
        edist[base + rank] = sqrtf(__fadd_rn(dm, 1e-8f));
      }
    }
  }
}

// ---------------------------------------------------------------------------
// Kernel 2: edge MLP (K=288 bf16 MFMA) + cutoff mask + per-node aggregate
// 8 waves/block (2/SIMD at VGPR<=256) — was 4 waves = 1/SIMD, latency-bound.
// ---------------------------------------------------------------------------
#define ENPW 8

__global__ __launch_bounds__(512, 2)
void edge_kernel(const float* __restrict__ h,
                 const int* __restrict__ eidx, const float* __restrict__ edist,
                 const float* __restrict__ ew1, const float* __restrict__ eb1,
                 const float* __restrict__ ew2, const float* __restrict__ eb2,
                 float* __restrict__ agg)
{
  __shared__ __attribute__((aligned(16))) short ewt1[128][296]; // [n][k] transposed
  __shared__ __attribute__((aligned(16))) short ewt2[128][136];
  __shared__ __attribute__((aligned(16))) short m1s[8][2048];   // per-wave 16x128 swizzled

  const int tid = threadIdx.x;
  for (int idx = tid; idx < 288 * 128; idx += 512) {
    int k = idx >> 7, n = idx & 127;
    ewt1[n][k] = (k < 276) ? f2bf(ew1[k * 128 + n]) : (short)0;
  }
  for (int idx = tid; idx < 128 * 128; idx += 512) {
    int k = idx >> 7, n = idx & 127;
    ewt2[n][k] = f2bf(ew2[k * 128 + n]);
  }
  __syncthreads();

  const int wv = tid >> 6, lane = tid & 63;
  const int lo = lane & 15, hi = lane >> 4;
  short* m1w = &m1s[wv][0];

  float b1v[8], b2v[8];
  #pragma unroll
  for (int nf = 0; nf < 8; ++nf) {
    b1v[nf] = eb1[nf * 16 + lo];
    b2v[nf] = eb2[nf * 16 + lo];
  }
  // hoisted swizzled-store bases: off = (wbase[q] + (nf<<5)) — nf add pre-XOR is
  // folded since nf<<5 bits(5-7) vs XOR bits(4-6) overlap only at bit 5-6; keep add-then-xor:
  int wbase[4];
  #pragma unroll
  for (int q = 0; q < 4; ++q) {
    int row = hi * 4 + q;
    wbase[q] = (row << 8) + (lo << 1);      // + (nf<<5), then ^ xmask[q]
  }
  int xmask[4];
  #pragma unroll
  for (int q = 0; q < 4; ++q) xmask[q] = (((hi * 4 + q) & 7) << 4);
  int rbase[4];
  #pragma unroll
  for (int kc = 0; kc < 4; ++kc)
    rbase[kc] = (((lo << 8) + ((kc * 32 + hi * 8) << 1)) ^ ((lo & 7) << 4));

  const f32x4 zero4 = {0.f, 0.f, 0.f, 0.f};

  for (int it = 0; it < ENPW; ++it) {
    const int node = (blockIdx.x * 8 + wv) * ENPW + it;   // 0..32767
    int jg = eidx[(size_t)node * KNN + lo];
    jg &= (NBATCH * NNODE - 1);                 // sanitize: never fault on bad idx
    const float de = edist[(size_t)node * KNN + lo];

    const float* hi_p = h + (size_t)node * HID;
    const float* hj_p = h + (size_t)jg * HID;
    short8 aI[4], aJ[4];
    #pragma unroll
    for (int kc = 0; kc < 4; ++kc) {
      aI[kc] = cv8(hi_p + kc*32 + hi*8);
      aJ[kc] = cv8(hj_p + kc*32 + hi*8);
    }
    short8 aR;
    #pragma unroll
    for (int e = 0; e < 8; ++e) {
      const int r = hi * 8 + e;
      float val = 0.0f;
      if (r < NRBF) {
        const float cr = (float)(r * (5.0 / 19.0));
        float tt = __fsub_rn(de, cr);
        val = __expf(-16.0f * __fmul_rn(tt, tt));
      }
      aR[e] = f2bf(val);
    }

    f32x4 acc1[8];
    #pragma unroll
    for (int nf = 0; nf < 8; ++nf) acc1[nf] = zero4;
    #pragma unroll
    for (int kc = 0; kc < 9; ++kc) {
      short8 a = (kc < 4) ? aI[kc] : ((kc < 8) ? aJ[kc - 4] : aR);
      #pragma unroll
      for (int nf = 0; nf < 8; ++nf) {
        short8 bfrag = *(const short8*)&ewt1[nf*16 + lo][kc*32 + hi*8];
        acc1[nf] = __builtin_amdgcn_mfma_f32_16x16x32_bf16(a, bfrag, acc1[nf], 0, 0, 0);
      }
    }

    // bias + SiLU -> m1 (bf16) into XOR-swizzled per-wave LDS tile [16][128]
    #pragma unroll
    for (int nf = 0; nf < 8; ++nf) {
      #pragma unroll
      for (int q = 0; q < 4; ++q) {
        float s = silu_f(acc1[nf][q] + b1v[nf]);
        int byteoff = (wbase[q] + (nf << 5)) ^ xmask[q];
        *(short*)((char*)m1w + byteoff) = f2bf(s);
      }
    }

    f32x4 acc2[8];
    #pragma unroll
    for (int nf = 0; nf < 8; ++nf) acc2[nf] = zero4;
    #pragma unroll
    for (int kc = 0; kc < 4; ++kc) {
      short8 a = *(const short8*)((char*)m1w + rbase[kc]);
      #pragma unroll
      for (int nf = 0; nf < 8; ++nf) {
        short8 bfrag = *(const short8*)&ewt2[nf*16 + lo][kc*32 + hi*8];
        acc2[nf] = __builtin_amdgcn_mfma_f32_16x16x32_bf16(a, bfrag, acc2[nf], 0, 0, 0);
      }
    }

    float dq[4];
    #pragma unroll
    for (int q = 0; q < 4; ++q) dq[q] = edist[(size_t)node * KNN + hi*4 + q];
    #pragma unroll
    for (int nf = 0; nf < 8; ++nf) {
      float s = 0.0f;
      #pragma unroll
      for (int q = 0; q < 4; ++q) {
        float m = silu_f(acc2[nf][q] + b2v[nf]);
        s += (dq[q] < 5.0f) ? m : 0.0f;   // cutoff mask
      }
      s += __shfl_xor(s, 16);
      s += __shfl_xor(s, 32);
      if (hi == 0) agg[(size_t)node * HID + nf*16 + lo] = s;   // f32
    }
  }
}

// ---------------------------------------------------------------------------
// Kernel 3: node MLP (K=256 bf16 MFMA) + residual + LayerNorm, f32 I/O
// agg == out (in-place): each wave reads only its own 16 rows before writing.
// 8 waves/block, grid 256 -> weights staged once per CU.
// ---------------------------------------------------------------------------
__global__ __launch_bounds__(512, 2)
void node_kernel(const float* __restrict__ h, const float* agg,
                 const float* __restrict__ nw1, const float* __restrict__ nb1,
                 const float* __restrict__ nw2, const float* __restrict__ nb2,
                 const float* __restrict__ gam, const float* __restrict__ bet,
                 float* out)
{
  __shared__ __attribute__((aligned(16))) short w1t[128][264];
  __shared__ __attribute__((aligned(16))) short w2t[128][136];
  __shared__ __attribute__((aligned(16))) short m1s[8][2048];

  const int tid = threadIdx.x;
  for (int idx = tid; idx < 256 * 128; idx += 512) {
    int k = idx >> 7, n = idx & 127;
    w1t[n][k] = f2bf(nw1[k * 128 + n]);
  }
  for (int idx = tid; idx < 128 * 128; idx += 512) {
    int k = idx >> 7, n = idx & 127;
    w2t[n][k] = f2bf(nw2[k * 128 + n]);
  }
  __syncthreads();

  const int wv = tid >> 6, lane = tid & 63;
  const int lo = lane & 15, hi = lane >> 4;
  short* m1w = &m1s[wv][0];

  float b1v[8], b2v[8], gv[8], bv[8];
  #pragma unroll
  for (int nf = 0; nf < 8; ++nf) {
    b1v[nf] = nb1[nf*16 + lo];
    b2v[nf] = nb2[nf*16 + lo];
    gv[nf]  = gam[nf*16 + lo];
    bv[nf]  = bet[nf*16 + lo];
  }
  const f32x4 zero4 = {0.f, 0.f, 0.f, 0.f};

  const int row0 = (blockIdx.x * 8 + wv) * 16;   // 0..32752

  const float* hrow = h   + (size_t)(row0 + lo) * HID;
  const float* arow = agg + (size_t)(row0 + lo) * HID;

  f32x4 acc1[8];
  #pragma unroll
  for (int nf = 0; nf < 8; ++nf) acc1[nf] = zero4;
  #pragma unroll
  for (int kc = 0; kc < 8; ++kc) {
    short8 a = (kc < 4) ? cv8(hrow + kc*32 + hi*8)
                        : cv8(arow + (kc - 4)*32 + hi*8);
    #pragma unroll
    for (int nf = 0; nf < 8; ++nf) {
      short8 bfrag = *(const short8*)&w1t[nf*16 + lo][kc*32 + hi*8];
      acc1[nf] = __builtin_amdgcn_mfma_f32_16x16x32_bf16(a, bfrag, acc1[nf], 0, 0, 0);
    }
  }

  #pragma unroll
  for (int nf = 0; nf < 8; ++nf) {
    #pragma unroll
    for (int q = 0; q < 4; ++q) {
      float s = silu_f(acc1[nf][q] + b1v[nf]);
      int row = hi * 4 + q, col = nf * 16 + lo;
      int byteoff = ((row << 8) + (col << 1)) ^ ((row & 7) << 4);
      *(short*)((char*)m1w + byteoff) = f2bf(s);
    }
  }

  f32x4 acc2[8];
  #pragma unroll
  for (int nf = 0; nf < 8; ++nf) acc2[nf] = zero4;
  #pragma unroll
  for (int kc = 0; kc < 4; ++kc) {
    int byteA = ((lo << 8) + ((kc*32 + hi*8) << 1)) ^ ((lo & 7) << 4);
    short8 a = *(const short8*)((char*)m1w + byteA);
    #pragma unroll
    for (int nf = 0; nf < 8; ++nf) {
      short8 bfrag = *(const short8*)&w2t[nf*16 + lo][kc*32 + hi*8];
      acc2[nf] = __builtin_amdgcn_mfma_f32_16x16x32_bf16(a, bfrag, acc2[nf], 0, 0, 0);
    }
  }

  // x = h + update (h added in exact f32); LayerNorm over 128 dims
  float xv[4][8];
  #pragma unroll
  for (int nf = 0; nf < 8; ++nf) {
    #pragma unroll
    for (int q = 0; q < 4; ++q) {
      xv[q][nf] = acc2[nf][q] + b2v[nf]
                + h[(size_t)(row0 + hi*4 + q) * HID + nf*16 + lo];
    }
  }

  #pragma unroll
  for (int q = 0; q < 4; ++q) {
    float s = 0.0f;
    #pragma unroll
    for (int nf = 0; nf < 8; ++nf) s += xv[q][nf];
    s += __shfl_xor(s, 1); s += __shfl_xor(s, 2);
    s += __shfl_xor(s, 4); s += __shfl_xor(s, 8);
    float mu = s * 0.0078125f;
    float t = 0.0f;
    #pragma unroll
    for (int nf = 0; nf < 8; ++nf) { float d = xv[q][nf] - mu; t += d * d; }
    t += __shfl_xor(t, 1); t += __shfl_xor(t, 2);
    t += __shfl_xor(t, 4); t += __shfl_xor(t, 8);
    float inv = 1.0f / sqrtf(t * 0.0078125f + 1e-5f);
    #pragma unroll
    for (int nf = 0; nf < 8; ++nf) {
      float y = (xv[q][nf] - mu) * inv * gv[nf] + bv[nf];
      out[(size_t)(row0 + hi*4 + q) * HID + nf*16 + lo] = y;
    }
  }
}

// ---------------------------------------------------------------------------
extern "C" void kernel_launch(void* const* d_in, const int* in_sizes, int n_in,
                              void* d_out, int out_size, void* d_ws, size_t ws_size,
                              hipStream_t stream) {
  (void)in_sizes; (void)n_in; (void)out_size;
  const float* h   = (const float*)d_in[0];
  const float* pos = (const float*)d_in[1];
  const float* ew1 = (const float*)d_in[2];
  const float* eb1 = (const float*)d_in[3];
  const float* ew2 = (const float*)d_in[4];
  const float* eb2 = (const float*)d_in[5];
  const float* nw1 = (const float*)d_in[6];
  const float* nb1 = (const float*)d_in[7];
  const float* nw2 = (const float*)d_in[8];
  const float* nb2 = (const float*)d_in[9];
  const float* gam = (const float*)d_in[10];
  const float* bet = (const float*)d_in[11];

  // ws: eidx 2MB | edist 2MB.  agg (f32 [8,4096,128]) lives in d_out; node in-place.
  const size_t need = (size_t)NBATCH * NNODE * KNN * 8;   // 4 MB
  if (ws_size < need) return;

  char* wsp = (char*)d_ws;
  int*   eidx  = (int*)wsp;
  float* edist = (float*)(wsp + (size_t)NBATCH * NNODE * KNN * 4);
  float* agg   = (float*)d_out;

  knn_kernel<<<dim3(1024), dim3(512), 0, stream>>>(pos, eidx, edist);
  edge_kernel<<<dim3(512), dim3(512), 0, stream>>>(h, eidx, edist, ew1, eb1, ew2, eb2, agg);
  node_kernel<<<dim3(256), dim3(512), 0, stream>>>(h, agg, nw1, nb1, nw2, nb2, gam, bet,
                                                   (float*)d_out);
}

// Round 5
// 562.251 us; speedup vs baseline: 1.0709x; 1.0709x over previous
//
#include <hip/hip_runtime.h>
#include <hip/hip_bf16.h>

#define HID 128
#define NRBF 20
#define KNN 16
#define NNODE 4096
#define NBATCH 8

typedef __attribute__((ext_vector_type(8))) short short8;
typedef __attribute__((ext_vector_type(4))) float f32x4;

__device__ __forceinline__ short f2bf(float x) {
  __hip_bfloat16 b = __float2bfloat16(x);   // RNE
  return __builtin_bit_cast(short, b);
}
__device__ __forceinline__ float silu_f(float x) {
  return x * __builtin_amdgcn_rcpf(1.0f + __expf(-x));  // ~1e-7 rel err, << bf16 rounding
}
// convert 8 consecutive f32 -> short8 of bf16
__device__ __forceinline__ short8 cv8(const float* p) {
  f32x4 a = *(const f32x4*)p;
  f32x4 b = *(const f32x4*)(p + 4);
  short8 r;
  r[0]=f2bf(a[0]); r[1]=f2bf(a[1]); r[2]=f2bf(a[2]); r[3]=f2bf(a[3]);
  r[4]=f2bf(b[0]); r[5]=f2bf(b[1]); r[6]=f2bf(b[2]); r[7]=f2bf(b[3]);
  return r;
}

// ---------------------------------------------------------------------------
// Kernel 1: exact kNN (top-16, stable index tiebreak), f32
// one wave per node; threshold = 16th smallest of per-lane strip minima.
// ---------------------------------------------------------------------------
__global__ __launch_bounds__(512)
void knn_kernel(const float* __restrict__ pos,
                int* __restrict__ eidx, float* __restrict__ edist)
{
  __shared__ f32x4 posL4[NNODE];     // 64 KB
  __shared__ float d2b[8][128];
  __shared__ int   jb[8][128];
  __shared__ int   cntL[8];

  const int tid  = threadIdx.x;
  const int wv   = tid >> 6;
  const int lane = tid & 63;
  const int b    = blockIdx.x >> 7;     // 128 blocks per batch
  const int grp  = blockIdx.x & 127;

  const float* pb = pos + (size_t)b * NNODE * 3;
  for (int idx = tid; idx < NNODE; idx += 512) {
    f32x4 v; v[0] = pb[idx*3]; v[1] = pb[idx*3+1]; v[2] = pb[idx*3+2]; v[3] = 0.f;
    posL4[idx] = v;
  }
  __syncthreads();

  for (int itn = 0; itn < 4; ++itn) {
    const int i = grp * 32 + wv * 4 + itn;
    const f32x4 pi = posL4[i];
    const float pix = pi[0], piy = pi[1], piz = pi[2];

    // pass 1: per-lane strip minima (numpy-exact f32 arithmetic, no FMA)
    float vmin = 3.0e38f;
    for (int t = 0; t < 64; ++t) {
      const int j = t * 64 + lane;
      f32x4 p = posL4[j];
      float dx = __fsub_rn(pix, p[0]);
      float dy = __fsub_rn(piy, p[1]);
      float dz = __fsub_rn(piz, p[2]);
      float d2 = __fadd_rn(__fadd_rn(__fmul_rn(dx,dx), __fmul_rn(dy,dy)), __fmul_rn(dz,dz));
      if (j == i) d2 = 3.0e38f;
      vmin = fminf(vmin, d2);
    }

    // bitonic sort the 64 lane minima (ascending); T = element 15
    float v = vmin;
    #pragma unroll
    for (int k = 2; k <= 64; k <<= 1) {
      #pragma unroll
      for (int jj = k >> 1; jj > 0; jj >>= 1) {
        float o = __shfl_xor(v, jj);
        const bool up   = ((lane & k) == 0);
        const bool lowl = ((lane & jj) == 0);
        float mn = fminf(v, o), mx = fmaxf(v, o);
        v = (up == lowl) ? mn : mx;
      }
    }
    const float T = __shfl(v, 15);   // >= true 16th smallest

    if (lane == 0) cntL[wv] = 0;
    // pass 2: compact candidates with d2 <= T (expected ~20-40)
    for (int t = 0; t < 64; ++t) {
      const int j = t * 64 + lane;
      f32x4 p = posL4[j];
      float dx = __fsub_rn(pix, p[0]);
      float dy = __fsub_rn(piy, p[1]);
      float dz = __fsub_rn(piz, p[2]);
      float d2 = __fadd_rn(__fadd_rn(__fmul_rn(dx,dx), __fmul_rn(dy,dy)), __fmul_rn(dz,dz));
      bool ok = (j != i) && (d2 <= T);
      if (ok) {
        int p2 = atomicAdd(&cntL[wv], 1);
        if (p2 < 128) { d2b[wv][p2] = d2; jb[wv][p2] = j; }
      }
    }
    int cnt = cntL[wv];
    if (cnt > 128) cnt = 128;

    // exact stable rank selection (ties -> lower index, matches top_k)
    for (int s = lane; s < cnt; s += 64) {
      float dm = d2b[wv][s]; int jm = jb[wv][s];
      int rank = 0;
      for (int c = 0; c < cnt; ++c) {
        float dc = d2b[wv][c]; int jc = jb[wv][c];
        if (dc < dm || (dc == dm && jc < jm)) ++rank;
      }
      if (rank < KNN) {
        size_t base = ((size_t)b * NNODE + i) * KNN;
        eidx[base + rank]  = b * NNODE + jm;          // global row index
        edist[base + rank] = sqrtf(__fadd_rn(dm, 1e-8f));
      }
    }
  }
}

// ---------------------------------------------------------------------------
// Kernel 2: edge MLP (K=288 bf16 MFMA) + cutoff mask + per-node aggregate
// 8 waves/block = 2 waves/SIMD (natural VGPR ~244, NO forced cap -> no spills).
// grid 256 = 1 block/CU: weights staged exactly once per CU.
// ---------------------------------------------------------------------------
#define ENPW 16

__global__ __launch_bounds__(512)
void edge_kernel(const float* __restrict__ h,
                 const int* __restrict__ eidx, const float* __restrict__ edist,
                 const float* __restrict__ ew1, const float* __restrict__ eb1,
                 const float* __restrict__ ew2, const float* __restrict__ eb2,
                 float* __restrict__ agg)
{
  __shared__ __attribute__((aligned(16))) short ewt1[128][296]; // [n][k] transposed
  __shared__ __attribute__((aligned(16))) short ewt2[128][136];
  __shared__ __attribute__((aligned(16))) short m1s[8][2048];   // per-wave 16x128 swizzled

  const int tid = threadIdx.x;
  for (int idx = tid; idx < 288 * 128; idx += 512) {
    int k = idx >> 7, n = idx & 127;
    ewt1[n][k] = (k < 276) ? f2bf(ew1[k * 128 + n]) : (short)0;
  }
  for (int idx = tid; idx < 128 * 128; idx += 512) {
    int k = idx >> 7, n = idx & 127;
    ewt2[n][k] = f2bf(ew2[k * 128 + n]);
  }
  __syncthreads();

  const int wv = tid >> 6, lane = tid & 63;
  const int lo = lane & 15, hi = lane >> 4;
  short* m1w = &m1s[wv][0];

  float b1v[8], b2v[8];
  #pragma unroll
  for (int nf = 0; nf < 8; ++nf) {
    b1v[nf] = eb1[nf * 16 + lo];
    b2v[nf] = eb2[nf * 16 + lo];
  }
  int wbase[4], xmask[4], rbase[4];
  #pragma unroll
  for (int q = 0; q < 4; ++q) {
    int row = hi * 4 + q;
    wbase[q] = (row << 8) + (lo << 1);
    xmask[q] = ((row & 7) << 4);
  }
  #pragma unroll
  for (int kc = 0; kc < 4; ++kc)
    rbase[kc] = (((lo << 8) + ((kc * 32 + hi * 8) << 1)) ^ ((lo & 7) << 4));

  const f32x4 zero4 = {0.f, 0.f, 0.f, 0.f};

  for (int it = 0; it < ENPW; ++it) {
    const int node = (blockIdx.x * 8 + wv) * ENPW + it;   // 0..32767
    int jg = eidx[(size_t)node * KNN + lo];
    jg &= (NBATCH * NNODE - 1);                 // sanitize: never fault on bad idx
    const float de = edist[(size_t)node * KNN + lo];

    const float* hi_p = h + (size_t)node * HID;
    const float* hj_p = h + (size_t)jg * HID;
    short8 aI[4], aJ[4];
    #pragma unroll
    for (int kc = 0; kc < 4; ++kc) {
      aI[kc] = cv8(hi_p + kc*32 + hi*8);
      aJ[kc] = cv8(hj_p + kc*32 + hi*8);
    }
    short8 aR;
    #pragma unroll
    for (int e = 0; e < 8; ++e) {
      const int r = hi * 8 + e;
      float val = 0.0f;
      if (r < NRBF) {
        const float cr = (float)(r * (5.0 / 19.0));
        float tt = __fsub_rn(de, cr);
        val = __expf(-16.0f * __fmul_rn(tt, tt));
      }
      aR[e] = f2bf(val);
    }

    f32x4 acc1[8];
    #pragma unroll
    for (int nf = 0; nf < 8; ++nf) acc1[nf] = zero4;
    #pragma unroll
    for (int kc = 0; kc < 9; ++kc) {
      short8 a = (kc < 4) ? aI[kc] : ((kc < 8) ? aJ[kc - 4] : aR);
      #pragma unroll
      for (int nf = 0; nf < 8; ++nf) {
        short8 bfrag = *(const short8*)&ewt1[nf*16 + lo][kc*32 + hi*8];
        acc1[nf] = __builtin_amdgcn_mfma_f32_16x16x32_bf16(a, bfrag, acc1[nf], 0, 0, 0);
      }
    }

    // bias + SiLU -> m1 (bf16) into XOR-swizzled per-wave LDS tile [16][128]
    #pragma unroll
    for (int nf = 0; nf < 8; ++nf) {
      #pragma unroll
      for (int q = 0; q < 4; ++q) {
        float s = silu_f(acc1[nf][q] + b1v[nf]);
        int byteoff = (wbase[q] + (nf << 5)) ^ xmask[q];
        *(short*)((char*)m1w + byteoff) = f2bf(s);
      }
    }

    f32x4 acc2[8];
    #pragma unroll
    for (int nf = 0; nf < 8; ++nf) acc2[nf] = zero4;
    #pragma unroll
    for (int kc = 0; kc < 4; ++kc) {
      short8 a = *(const short8*)((char*)m1w + rbase[kc]);
      #pragma unroll
      for (int nf = 0; nf < 8; ++nf) {
        short8 bfrag = *(const short8*)&ewt2[nf*16 + lo][kc*32 + hi*8];
        acc2[nf] = __builtin_amdgcn_mfma_f32_16x16x32_bf16(a, bfrag, acc2[nf], 0, 0, 0);
      }
    }

    float dq[4];
    #pragma unroll
    for (int q = 0; q < 4; ++q) dq[q] = edist[(size_t)node * KNN + hi*4 + q];
    #pragma unroll
    for (int nf = 0; nf < 8; ++nf) {
      float s = 0.0f;
      #pragma unroll
      for (int q = 0; q < 4; ++q) {
        float m = silu_f(acc2[nf][q] + b2v[nf]);
        s += (dq[q] < 5.0f) ? m : 0.0f;   // cutoff mask
      }
      s += __shfl_xor(s, 16);
      s += __shfl_xor(s, 32);
      if (hi == 0) agg[(size_t)node * HID + nf*16 + lo] = s;   // f32
    }
  }
}

// ---------------------------------------------------------------------------
// Kernel 3: node MLP (K=256 bf16 MFMA) + residual + LayerNorm, f32 I/O
// agg == out (in-place): each wave reads only its own 16 rows before writing.
// ---------------------------------------------------------------------------
__global__ __launch_bounds__(512)
void node_kernel(const float* __restrict__ h, const float* agg,
                 const float* __restrict__ nw1, const float* __restrict__ nb1,
                 const float* __restrict__ nw2, const float* __restrict__ nb2,
                 const float* __restrict__ gam, const float* __restrict__ bet,
                 float* out)
{
  __shared__ __attribute__((aligned(16))) short w1t[128][264];
  __shared__ __attribute__((aligned(16))) short w2t[128][136];
  __shared__ __attribute__((aligned(16))) short m1s[8][2048];

  const int tid = threadIdx.x;
  for (int idx = tid; idx < 256 * 128; idx += 512) {
    int k = idx >> 7, n = idx & 127;
    w1t[n][k] = f2bf(nw1[k * 128 + n]);
  }
  for (int idx = tid; idx < 128 * 128; idx += 512) {
    int k = idx >> 7, n = idx & 127;
    w2t[n][k] = f2bf(nw2[k * 128 + n]);
  }
  __syncthreads();

  const int wv = tid >> 6, lane = tid & 63;
  const int lo = lane & 15, hi = lane >> 4;
  short* m1w = &m1s[wv][0];

  float b1v[8], b2v[8], gv[8], bv[8];
  #pragma unroll
  for (int nf = 0; nf < 8; ++nf) {
    b1v[nf] = nb1[nf*16 + lo];
    b2v[nf] = nb2[nf*16 + lo];
    gv[nf]  = gam[nf*16 + lo];
    bv[nf]  = bet[nf*16 + lo];
  }
  const f32x4 zero4 = {0.f, 0.f, 0.f, 0.f};

  const int row0 = (blockIdx.x * 8 + wv) * 16;   // 0..32752

  const float* hrow = h   + (size_t)(row0 + lo) * HID;
  const float* arow = agg + (size_t)(row0 + lo) * HID;

  f32x4 acc1[8];
  #pragma unroll
  for (int nf = 0; nf < 8; ++nf) acc1[nf] = zero4;
  #pragma unroll
  for (int kc = 0; kc < 8; ++kc) {
    short8 a = (kc < 4) ? cv8(hrow + kc*32 + hi*8)
                        : cv8(arow + (kc - 4)*32 + hi*8);
    #pragma unroll
    for (int nf = 0; nf < 8; ++nf) {
      short8 bfrag = *(const short8*)&w1t[nf*16 + lo][kc*32 + hi*8];
      acc1[nf] = __builtin_amdgcn_mfma_f32_16x16x32_bf16(a, bfrag, acc1[nf], 0, 0, 0);
    }
  }

  #pragma unroll
  for (int nf = 0; nf < 8; ++nf) {
    #pragma unroll
    for (int q = 0; q < 4; ++q) {
      float s = silu_f(acc1[nf][q] + b1v[nf]);
      int row = hi * 4 + q, col = nf * 16 + lo;
      int byteoff = ((row << 8) + (col << 1)) ^ ((row & 7) << 4);
      *(short*)((char*)m1w + byteoff) = f2bf(s);
    }
  }

  f32x4 acc2[8];
  #pragma unroll
  for (int nf = 0; nf < 8; ++nf) acc2[nf] = zero4;
  #pragma unroll
  for (int kc = 0; kc < 4; ++kc) {
    int byteA = ((lo << 8) + ((kc*32 + hi*8) << 1)) ^ ((lo & 7) << 4);
    short8 a = *(const short8*)((char*)m1w + byteA);
    #pragma unroll
    for (int nf = 0; nf < 8; ++nf) {
      short8 bfrag = *(const short8*)&w2t[nf*16 + lo][kc*32 + hi*8];
      acc2[nf] = __builtin_amdgcn_mfma_f32_16x16x32_bf16(a, bfrag, acc2[nf], 0, 0, 0);
    }
  }

  // x = h + update (h added in exact f32); LayerNorm over 128 dims
  float xv[4][8];
  #pragma unroll
  for (int nf = 0; nf < 8; ++nf) {
    #pragma unroll
    for (int q = 0; q < 4; ++q) {
      xv[q][nf] = acc2[nf][q] + b2v[nf]
                + h[(size_t)(row0 + hi*4 + q) * HID + nf*16 + lo];
    }
  }

  #pragma unroll
  for (int q = 0; q < 4; ++q) {
    float s = 0.0f;
    #pragma unroll
    for (int nf = 0; nf < 8; ++nf) s += xv[q][nf];
    s += __shfl_xor(s, 1); s += __shfl_xor(s, 2);
    s += __shfl_xor(s, 4); s += __shfl_xor(s, 8);
    float mu = s * 0.0078125f;
    float t = 0.0f;
    #pragma unroll
    for (int nf = 0; nf < 8; ++nf) { float d = xv[q][nf] - mu; t += d * d; }
    t += __shfl_xor(t, 1); t += __shfl_xor(t, 2);
    t += __shfl_xor(t, 4); t += __shfl_xor(t, 8);
    float inv = 1.0f / sqrtf(t * 0.0078125f + 1e-5f);
    #pragma unroll
    for (int nf = 0; nf < 8; ++nf) {
      float y = (xv[q][nf] - mu) * inv * gv[nf] + bv[nf];
      out[(size_t)(row0 + hi*4 + q) * HID + nf*16 + lo] = y;
    }
  }
}

// ---------------------------------------------------------------------------
extern "C" void kernel_launch(void* const* d_in, const int* in_sizes, int n_in,
                              void* d_out, int out_size, void* d_ws, size_t ws_size,
                              hipStream_t stream) {
  (void)in_sizes; (void)n_in; (void)out_size;
  const float* h   = (const float*)d_in[0];
  const float* pos = (const float*)d_in[1];
  const float* ew1 = (const float*)d_in[2];
  const float* eb1 = (const float*)d_in[3];
  const float* ew2 = (const float*)d_in[4];
  const float* eb2 = (const float*)d_in[5];
  const float* nw1 = (const float*)d_in[6];
  const float* nb1 = (const float*)d_in[7];
  const float* nw2 = (const float*)d_in[8];
  const float* nb2 = (const float*)d_in[9];
  const float* gam = (const float*)d_in[10];
  const float* bet = (const float*)d_in[11];

  // ws: eidx 2MB | edist 2MB.  agg (f32 [8,4096,128]) lives in d_out; node in-place.
  const size_t need = (size_t)NBATCH * NNODE * KNN * 8;   // 4 MB
  if (ws_size < need) return;

  char* wsp = (char*)d_ws;
  int*   eidx  = (int*)wsp;
  float* edist = (float*)(wsp + (size_t)NBATCH * NNODE * KNN * 4);
  float* agg   = (float*)d_out;

  knn_kernel<<<dim3(1024), dim3(512), 0, stream>>>(pos, eidx, edist);
  edge_kernel<<<dim3(256), dim3(512), 0, stream>>>(h, eidx, edist, ew1, eb1, ew2, eb2, agg);
  node_kernel<<<dim3(256), dim3(512), 0, stream>>>(h, agg, nw1, nb1, nw2, nb2, gam, bet,
                                                   (float*)d_out);
}

// Round 6
// 423.272 us; speedup vs baseline: 1.4226x; 1.3283x over previous
//
#include <hip/hip_runtime.h>
#include <hip/hip_bf16.h>

#define HID 128
#define NRBF 20
#define KNN 16
#define NNODE 4096
#define NBATCH 8

typedef __attribute__((ext_vector_type(8))) short short8;
typedef __attribute__((ext_vector_type(4))) float f32x4;

__device__ __forceinline__ short f2bf(float x) {
  __hip_bfloat16 b = __float2bfloat16(x);   // RNE
  return __builtin_bit_cast(short, b);
}
__device__ __forceinline__ float silu_f(float x) {
  return x * __builtin_amdgcn_rcpf(1.0f + __expf(-x));  // ~1e-7 rel err << bf16 rounding
}
__device__ __forceinline__ short8 cv8(const float* p) {
  f32x4 a = *(const f32x4*)p;
  f32x4 b = *(const f32x4*)(p + 4);
  short8 r;
  r[0]=f2bf(a[0]); r[1]=f2bf(a[1]); r[2]=f2bf(a[2]); r[3]=f2bf(a[3]);
  r[4]=f2bf(b[0]); r[5]=f2bf(b[1]); r[6]=f2bf(b[2]); r[7]=f2bf(b[3]);
  return r;
}

// ---------------------------------------------------------------------------
// Kernel 1: exact kNN (top-16, stable index tiebreak), f32 — unchanged.
// ---------------------------------------------------------------------------
__global__ __launch_bounds__(512)
void knn_kernel(const float* __restrict__ pos,
                int* __restrict__ eidx, float* __restrict__ edist)
{
  __shared__ f32x4 posL4[NNODE];     // 64 KB
  __shared__ float d2b[8][128];
  __shared__ int   jb[8][128];
  __shared__ int   cntL[8];

  const int tid  = threadIdx.x;
  const int wv   = tid >> 6;
  const int lane = tid & 63;
  const int b    = blockIdx.x >> 7;
  const int grp  = blockIdx.x & 127;

  const float* pb = pos + (size_t)b * NNODE * 3;
  for (int idx = tid; idx < NNODE; idx += 512) {
    f32x4 v; v[0] = pb[idx*3]; v[1] = pb[idx*3+1]; v[2] = pb[idx*3+2]; v[3] = 0.f;
    posL4[idx] = v;
  }
  __syncthreads();

  for (int itn = 0; itn < 4; ++itn) {
    const int i = grp * 32 + wv * 4 + itn;
    const f32x4 pi = posL4[i];
    const float pix = pi[0], piy = pi[1], piz = pi[2];

    float vmin = 3.0e38f;
    for (int t = 0; t < 64; ++t) {
      const int j = t * 64 + lane;
      f32x4 p = posL4[j];
      float dx = __fsub_rn(pix, p[0]);
      float dy = __fsub_rn(piy, p[1]);
      float dz = __fsub_rn(piz, p[2]);
      float d2 = __fadd_rn(__fadd_rn(__fmul_rn(dx,dx), __fmul_rn(dy,dy)), __fmul_rn(dz,dz));
      if (j == i) d2 = 3.0e38f;
      vmin = fminf(vmin, d2);
    }

    float v = vmin;
    #pragma unroll
    for (int k = 2; k <= 64; k <<= 1) {
      #pragma unroll
      for (int jj = k >> 1; jj > 0; jj >>= 1) {
        float o = __shfl_xor(v, jj);
        const bool up   = ((lane & k) == 0);
        const bool lowl = ((lane & jj) == 0);
        float mn = fminf(v, o), mx = fmaxf(v, o);
        v = (up == lowl) ? mn : mx;
      }
    }
    const float T = __shfl(v, 15);

    if (lane == 0) cntL[wv] = 0;
    for (int t = 0; t < 64; ++t) {
      const int j = t * 64 + lane;
      f32x4 p = posL4[j];
      float dx = __fsub_rn(pix, p[0]);
      float dy = __fsub_rn(piy, p[1]);
      float dz = __fsub_rn(piz, p[2]);
      float d2 = __fadd_rn(__fadd_rn(__fmul_rn(dx,dx), __fmul_rn(dy,dy)), __fmul_rn(dz,dz));
      bool ok = (j != i) && (d2 <= T);
      if (ok) {
        int p2 = atomicAdd(&cntL[wv], 1);
        if (p2 < 128) { d2b[wv][p2] = d2; jb[wv][p2] = j; }
      }
    }
    int cnt = cntL[wv];
    if (cnt > 128) cnt = 128;

    for (int s = lane; s < cnt; s += 64) {
      float dm = d2b[wv][s]; int jm = jb[wv][s];
      int rank = 0;
      for (int c = 0; c < cnt; ++c) {
        float dc = d2b[wv][c]; int jc = jb[wv][c];
        if (dc < dm || (dc == dm && jc < jm)) ++rank;
      }
      if (rank < KNN) {
        size_t base = ((size_t)b * NNODE + i) * KNN;
        eidx[base + rank]  = b * NNODE + jm;
        edist[base + rank] = sqrtf(__fadd_rn(dm, 1e-8f));
      }
    }
  }
}

// ---------------------------------------------------------------------------
// Kernel 2: edge MLP + mask + aggregate.
// 256-thread/4-wave blocks (VGPR-safe), ILP-2 (two nodes in flight per wave),
// fragment-linear weight LDS: F[kc][nf][lane] short8 — conflict-free staging
// writes (lane-consecutive b128) and conflict-free MFMA B-reads.
// ---------------------------------------------------------------------------
#define ENPW 16

__global__ __launch_bounds__(256)
void edge_kernel(const float* __restrict__ h,
                 const int* __restrict__ eidx, const float* __restrict__ edist,
                 const float* __restrict__ ew1, const float* __restrict__ eb1,
                 const float* __restrict__ ew2, const float* __restrict__ eb2,
                 float* __restrict__ agg)
{
  __shared__ __attribute__((aligned(16))) short8 F1[9*8*64];     // 73,728 B
  __shared__ __attribute__((aligned(16))) short8 F2[4*8*64];     // 32,768 B
  __shared__ __attribute__((aligned(16))) short m1s[4][2][2048]; // 32,768 B

  const int tid = threadIdx.x;
  // stage ew1 -> F1 (bf16, fragment-linear), zero-pad k>=276
  for (int f = tid; f < 9*8*64; f += 256) {
    int kc = f >> 9, rem = f & 511, nf = rem >> 6, ln = rem & 63;
    int kb = kc*32 + (ln >> 4)*8, col = nf*16 + (ln & 15);
    short8 v;
    #pragma unroll
    for (int e = 0; e < 8; ++e) {
      int k = kb + e;
      v[e] = (k < 276) ? f2bf(ew1[k*128 + col]) : (short)0;
    }
    F1[f] = v;
  }
  for (int f = tid; f < 4*8*64; f += 256) {
    int kc = f >> 9, rem = f & 511, nf = rem >> 6, ln = rem & 63;
    int kb = kc*32 + (ln >> 4)*8, col = nf*16 + (ln & 15);
    short8 v;
    #pragma unroll
    for (int e = 0; e < 8; ++e) v[e] = f2bf(ew2[(kb + e)*128 + col]);
    F2[f] = v;
  }
  __syncthreads();

  const int wv = tid >> 6, lane = tid & 63;
  const int lo = lane & 15, hi = lane >> 4;
  short* m1A = &m1s[wv][0][0];
  short* m1B = &m1s[wv][1][0];

  float b1v[8], b2v[8];
  #pragma unroll
  for (int nf = 0; nf < 8; ++nf) {
    b1v[nf] = eb1[nf*16 + lo];
    b2v[nf] = eb2[nf*16 + lo];
  }
  int wbase[4], xmask[4], rbase[4];
  #pragma unroll
  for (int q = 0; q < 4; ++q) {
    int row = hi*4 + q;
    wbase[q] = (row << 8) + (lo << 1);
    xmask[q] = (row & 7) << 4;
  }
  #pragma unroll
  for (int kc = 0; kc < 4; ++kc)
    rbase[kc] = ((lo << 8) + ((kc*32 + hi*8) << 1)) ^ ((lo & 7) << 4);

  const f32x4 zero4 = {0.f, 0.f, 0.f, 0.f};
  const int nbase = (blockIdx.x * 4 + wv) * ENPW;

  #pragma unroll 1
  for (int it = 0; it < ENPW/2; ++it) {
    const int nA = nbase + it*2, nB = nA + 1;
    int jgA = eidx[(size_t)nA*KNN + lo] & (NBATCH*NNODE - 1);
    int jgB = eidx[(size_t)nB*KNN + lo] & (NBATCH*NNODE - 1);
    const float deA = edist[(size_t)nA*KNN + lo];
    const float deB = edist[(size_t)nB*KNN + lo];

    short8 aIA[4], aJA[4], aIB[4], aJB[4];
    #pragma unroll
    for (int kc = 0; kc < 4; ++kc) {
      aIA[kc] = cv8(h + (size_t)nA*HID  + kc*32 + hi*8);
      aJA[kc] = cv8(h + (size_t)jgA*HID + kc*32 + hi*8);
      aIB[kc] = cv8(h + (size_t)nB*HID  + kc*32 + hi*8);
      aJB[kc] = cv8(h + (size_t)jgB*HID + kc*32 + hi*8);
    }
    short8 aRA, aRB;
    #pragma unroll
    for (int e = 0; e < 8; ++e) {
      const int r = hi*8 + e;
      float vA = 0.f, vB = 0.f;
      if (r < NRBF) {
        const float cr = (float)(r * (5.0/19.0));
        float tA = __fsub_rn(deA, cr), tB = __fsub_rn(deB, cr);
        vA = __expf(-16.0f * __fmul_rn(tA, tA));
        vB = __expf(-16.0f * __fmul_rn(tB, tB));
      }
      aRA[e] = f2bf(vA); aRB[e] = f2bf(vB);
    }

    f32x4 acc1A[8], acc1B[8];
    #pragma unroll
    for (int nf = 0; nf < 8; ++nf) { acc1A[nf] = zero4; acc1B[nf] = zero4; }
    #pragma unroll
    for (int kc = 0; kc < 9; ++kc) {
      short8 aA = (kc < 4) ? aIA[kc] : ((kc < 8) ? aJA[kc-4] : aRA);
      short8 aB = (kc < 4) ? aIB[kc] : ((kc < 8) ? aJB[kc-4] : aRB);
      #pragma unroll
      for (int nf = 0; nf < 8; ++nf) {
        short8 bf = F1[(kc*8 + nf)*64 + lane];     // one read feeds 2 MFMAs
        acc1A[nf] = __builtin_amdgcn_mfma_f32_16x16x32_bf16(aA, bf, acc1A[nf], 0,0,0);
        acc1B[nf] = __builtin_amdgcn_mfma_f32_16x16x32_bf16(aB, bf, acc1B[nf], 0,0,0);
      }
    }

    #pragma unroll
    for (int nf = 0; nf < 8; ++nf) {
      #pragma unroll
      for (int q = 0; q < 4; ++q) {
        int off = (wbase[q] + (nf << 5)) ^ xmask[q];
        *(short*)((char*)m1A + off) = f2bf(silu_f(acc1A[nf][q] + b1v[nf]));
        *(short*)((char*)m1B + off) = f2bf(silu_f(acc1B[nf][q] + b1v[nf]));
      }
    }

    f32x4 acc2A[8], acc2B[8];
    #pragma unroll
    for (int nf = 0; nf < 8; ++nf) { acc2A[nf] = zero4; acc2B[nf] = zero4; }
    #pragma unroll
    for (int kc = 0; kc < 4; ++kc) {
      short8 aA = *(const short8*)((char*)m1A + rbase[kc]);
      short8 aB = *(const short8*)((char*)m1B + rbase[kc]);
      #pragma unroll
      for (int nf = 0; nf < 8; ++nf) {
        short8 bf = F2[(kc*8 + nf)*64 + lane];
        acc2A[nf] = __builtin_amdgcn_mfma_f32_16x16x32_bf16(aA, bf, acc2A[nf], 0,0,0);
        acc2B[nf] = __builtin_amdgcn_mfma_f32_16x16x32_bf16(aB, bf, acc2B[nf], 0,0,0);
      }
    }

    float dqA[4], dqB[4];
    #pragma unroll
    for (int q = 0; q < 4; ++q) {
      dqA[q] = edist[(size_t)nA*KNN + hi*4 + q];
      dqB[q] = edist[(size_t)nB*KNN + hi*4 + q];
    }
    #pragma unroll
    for (int nf = 0; nf < 8; ++nf) {
      float sA = 0.f, sB = 0.f;
      #pragma unroll
      for (int q = 0; q < 4; ++q) {
        float mA = silu_f(acc2A[nf][q] + b2v[nf]);
        float mB = silu_f(acc2B[nf][q] + b2v[nf]);
        sA += (dqA[q] < 5.0f) ? mA : 0.f;
        sB += (dqB[q] < 5.0f) ? mB : 0.f;
      }
      sA += __shfl_xor(sA, 16); sA += __shfl_xor(sA, 32);
      sB += __shfl_xor(sB, 16); sB += __shfl_xor(sB, 32);
      if (hi == 0) {
        agg[(size_t)nA*HID + nf*16 + lo] = sA;
        agg[(size_t)nB*HID + nf*16 + lo] = sB;
      }
    }
  }
}

// ---------------------------------------------------------------------------
// Kernel 3: node MLP + residual + LayerNorm, f32 I/O, agg==out in-place.
// 256-thread blocks, fragment-linear weight LDS.
// ---------------------------------------------------------------------------
__global__ __launch_bounds__(256)
void node_kernel(const float* __restrict__ h, const float* agg,
                 const float* __restrict__ nw1, const float* __restrict__ nb1,
                 const float* __restrict__ nw2, const float* __restrict__ nb2,
                 const float* __restrict__ gam, const float* __restrict__ bet,
                 float* out)
{
  __shared__ __attribute__((aligned(16))) short8 G1[8*8*64];   // 65,536 B
  __shared__ __attribute__((aligned(16))) short8 G2[4*8*64];   // 32,768 B
  __shared__ __attribute__((aligned(16))) short m1s[4][2048];  // 16,384 B

  const int tid = threadIdx.x;
  for (int f = tid; f < 8*8*64; f += 256) {
    int kc = f >> 9, rem = f & 511, nf = rem >> 6, ln = rem & 63;
    int kb = kc*32 + (ln >> 4)*8, col = nf*16 + (ln & 15);
    short8 v;
    #pragma unroll
    for (int e = 0; e < 8; ++e) v[e] = f2bf(nw1[(kb + e)*128 + col]);
    G1[f] = v;
  }
  for (int f = tid; f < 4*8*64; f += 256) {
    int kc = f >> 9, rem = f & 511, nf = rem >> 6, ln = rem & 63;
    int kb = kc*32 + (ln >> 4)*8, col = nf*16 + (ln & 15);
    short8 v;
    #pragma unroll
    for (int e = 0; e < 8; ++e) v[e] = f2bf(nw2[(kb + e)*128 + col]);
    G2[f] = v;
  }
  __syncthreads();

  const int wv = tid >> 6, lane = tid & 63;
  const int lo = lane & 15, hi = lane >> 4;
  short* m1w = &m1s[wv][0];

  float b1v[8], b2v[8], gv[8], bv[8];
  #pragma unroll
  for (int nf = 0; nf < 8; ++nf) {
    b1v[nf] = nb1[nf*16 + lo];
    b2v[nf] = nb2[nf*16 + lo];
    gv[nf]  = gam[nf*16 + lo];
    bv[nf]  = bet[nf*16 + lo];
  }
  const f32x4 zero4 = {0.f, 0.f, 0.f, 0.f};

  const int row0 = (blockIdx.x * 4 + wv) * 16;

  const float* hrow = h   + (size_t)(row0 + lo) * HID;
  const float* arow = agg + (size_t)(row0 + lo) * HID;

  f32x4 acc1[8];
  #pragma unroll
  for (int nf = 0; nf < 8; ++nf) acc1[nf] = zero4;
  #pragma unroll
  for (int kc = 0; kc < 8; ++kc) {
    short8 a = (kc < 4) ? cv8(hrow + kc*32 + hi*8)
                        : cv8(arow + (kc - 4)*32 + hi*8);
    #pragma unroll
    for (int nf = 0; nf < 8; ++nf) {
      short8 bf = G1[(kc*8 + nf)*64 + lane];
      acc1[nf] = __builtin_amdgcn_mfma_f32_16x16x32_bf16(a, bf, acc1[nf], 0,0,0);
    }
  }

  #pragma unroll
  for (int nf = 0; nf < 8; ++nf) {
    #pragma unroll
    for (int q = 0; q < 4; ++q) {
      float s = silu_f(acc1[nf][q] + b1v[nf]);
      int row = hi*4 + q, col = nf*16 + lo;
      int byteoff = ((row << 8) + (col << 1)) ^ ((row & 7) << 4);
      *(short*)((char*)m1w + byteoff) = f2bf(s);
    }
  }

  f32x4 acc2[8];
  #pragma unroll
  for (int nf = 0; nf < 8; ++nf) acc2[nf] = zero4;
  #pragma unroll
  for (int kc = 0; kc < 4; ++kc) {
    int byteA = ((lo << 8) + ((kc*32 + hi*8) << 1)) ^ ((lo & 7) << 4);
    short8 a = *(const short8*)((char*)m1w + byteA);
    #pragma unroll
    for (int nf = 0; nf < 8; ++nf) {
      short8 bf = G2[(kc*8 + nf)*64 + lane];
      acc2[nf] = __builtin_amdgcn_mfma_f32_16x16x32_bf16(a, bf, acc2[nf], 0,0,0);
    }
  }

  float xv[4][8];
  #pragma unroll
  for (int nf = 0; nf < 8; ++nf) {
    #pragma unroll
    for (int q = 0; q < 4; ++q) {
      xv[q][nf] = acc2[nf][q] + b2v[nf]
                + h[(size_t)(row0 + hi*4 + q) * HID + nf*16 + lo];
    }
  }

  #pragma unroll
  for (int q = 0; q < 4; ++q) {
    float s = 0.0f;
    #pragma unroll
    for (int nf = 0; nf < 8; ++nf) s += xv[q][nf];
    s += __shfl_xor(s, 1); s += __shfl_xor(s, 2);
    s += __shfl_xor(s, 4); s += __shfl_xor(s, 8);
    float mu = s * 0.0078125f;
    float t = 0.0f;
    #pragma unroll
    for (int nf = 0; nf < 8; ++nf) { float d = xv[q][nf] - mu; t += d * d; }
    t += __shfl_xor(t, 1); t += __shfl_xor(t, 2);
    t += __shfl_xor(t, 4); t += __shfl_xor(t, 8);
    float inv = 1.0f / sqrtf(t * 0.0078125f + 1e-5f);
    #pragma unroll
    for (int nf = 0; nf < 8; ++nf) {
      float y = (xv[q][nf] - mu) * inv * gv[nf] + bv[nf];
      out[(size_t)(row0 + hi*4 + q) * HID + nf*16 + lo] = y;
    }
  }
}

// ---------------------------------------------------------------------------
extern "C" void kernel_launch(void* const* d_in, const int* in_sizes, int n_in,
                              void* d_out, int out_size, void* d_ws, size_t ws_size,
                              hipStream_t stream) {
  (void)in_sizes; (void)n_in; (void)out_size;
  const float* h   = (const float*)d_in[0];
  const float* pos = (const float*)d_in[1];
  const float* ew1 = (const float*)d_in[2];
  const float* eb1 = (const float*)d_in[3];
  const float* ew2 = (const float*)d_in[4];
  const float* eb2 = (const float*)d_in[5];
  const float* nw1 = (const float*)d_in[6];
  const float* nb1 = (const float*)d_in[7];
  const float* nw2 = (const float*)d_in[8];
  const float* nb2 = (const float*)d_in[9];
  const float* gam = (const float*)d_in[10];
  const float* bet = (const float*)d_in[11];

  const size_t need = (size_t)NBATCH * NNODE * KNN * 8;   // 4 MB
  if (ws_size < need) return;

  char* wsp = (char*)d_ws;
  int*   eidx  = (int*)wsp;
  float* edist = (float*)(wsp + (size_t)NBATCH * NNODE * KNN * 4);
  float* agg   = (float*)d_out;

  knn_kernel<<<dim3(1024), dim3(512), 0, stream>>>(pos, eidx, edist);
  edge_kernel<<<dim3(512), dim3(256), 0, stream>>>(h, eidx, edist, ew1, eb1, ew2, eb2, agg);
  node_kernel<<<dim3(512), dim3(256), 0, stream>>>(h, agg, nw1, nb1, nw2, nb2, gam, bet,
                                                   (float*)d_out);
}

// Round 7
// 237.269 us; speedup vs baseline: 2.5378x; 1.7839x over previous
//
#include <hip/hip_runtime.h>
#include <hip/hip_bf16.h>

#define HID 128
#define NRBF 20
#define KNN 16
#define NNODE 4096
#define NBATCH 8

typedef __attribute__((ext_vector_type(8))) short short8;
typedef __attribute__((ext_vector_type(4))) float f32x4;

__device__ __forceinline__ short f2bf(float x) {
  __hip_bfloat16 b = __float2bfloat16(x);   // RNE
  return __builtin_bit_cast(short, b);
}
__device__ __forceinline__ float silu_f(float x) {
  return x * __builtin_amdgcn_rcpf(1.0f + __expf(-x));  // ~1e-7 rel err << bf16 rounding
}
__device__ __forceinline__ short8 cv8(const float* p) {
  f32x4 a = *(const f32x4*)p;
  f32x4 b = *(const f32x4*)(p + 4);
  short8 r;
  r[0]=f2bf(a[0]); r[1]=f2bf(a[1]); r[2]=f2bf(a[2]); r[3]=f2bf(a[3]);
  r[4]=f2bf(b[0]); r[5]=f2bf(b[1]); r[6]=f2bf(b[2]); r[7]=f2bf(b[3]);
  return r;
}

// ---------------------------------------------------------------------------
// Kernel 1: exact kNN (top-16, stable index tiebreak), f32.
// Pass-1 batched across the wave's 4 nodes: 1 LDS read feeds 4 d2 chains
// (5 full scans instead of 8). Arithmetic bit-identical to numpy f32.
// ---------------------------------------------------------------------------
__global__ __launch_bounds__(512)
void knn_kernel(const float* __restrict__ pos,
                int* __restrict__ eidx, float* __restrict__ edist)
{
  __shared__ f32x4 posL4[NNODE];     // 64 KB
  __shared__ float d2b[8][128];
  __shared__ int   jb[8][128];
  __shared__ int   cntL[8];

  const int tid  = threadIdx.x;
  const int wv   = tid >> 6;
  const int lane = tid & 63;
  const int b    = blockIdx.x >> 7;
  const int grp  = blockIdx.x & 127;

  const float* pb = pos + (size_t)b * NNODE * 3;
  for (int idx = tid; idx < NNODE; idx += 512) {
    f32x4 v; v[0] = pb[idx*3]; v[1] = pb[idx*3+1]; v[2] = pb[idx*3+2]; v[3] = 0.f;
    posL4[idx] = v;
  }
  __syncthreads();

  const int i0 = grp * 32 + wv * 4;
  f32x4 pn[4];
  #pragma unroll
  for (int n = 0; n < 4; ++n) pn[n] = posL4[i0 + n];

  // pass 1 (batched): per-lane strip minima for all 4 nodes
  float vmin[4] = {3.0e38f, 3.0e38f, 3.0e38f, 3.0e38f};
  for (int t = 0; t < 64; ++t) {
    const int j = t * 64 + lane;
    f32x4 p = posL4[j];
    #pragma unroll
    for (int n = 0; n < 4; ++n) {
      float dx = __fsub_rn(pn[n][0], p[0]);
      float dy = __fsub_rn(pn[n][1], p[1]);
      float dz = __fsub_rn(pn[n][2], p[2]);
      float d2 = __fadd_rn(__fadd_rn(__fmul_rn(dx,dx), __fmul_rn(dy,dy)), __fmul_rn(dz,dz));
      if (j == i0 + n) d2 = 3.0e38f;
      vmin[n] = fminf(vmin[n], d2);
    }
  }

  // per-node: bitonic threshold, compaction scan, exact stable selection
  float Ts[4];
  #pragma unroll
  for (int n = 0; n < 4; ++n) {
    float v = vmin[n];
    #pragma unroll
    for (int k = 2; k <= 64; k <<= 1) {
      #pragma unroll
      for (int jj = k >> 1; jj > 0; jj >>= 1) {
        float o = __shfl_xor(v, jj);
        const bool up   = ((lane & k) == 0);
        const bool lowl = ((lane & jj) == 0);
        float mn = fminf(v, o), mx = fmaxf(v, o);
        v = (up == lowl) ? mn : mx;
      }
    }
    Ts[n] = __shfl(v, 15);   // >= true 16th smallest
  }

  #pragma unroll 1
  for (int n = 0; n < 4; ++n) {
    const int i = i0 + n;
    const float pix = pn[n][0], piy = pn[n][1], piz = pn[n][2];
    const float T = Ts[n];

    if (lane == 0) cntL[wv] = 0;
    for (int t = 0; t < 64; ++t) {
      const int j = t * 64 + lane;
      f32x4 p = posL4[j];
      float dx = __fsub_rn(pix, p[0]);
      float dy = __fsub_rn(piy, p[1]);
      float dz = __fsub_rn(piz, p[2]);
      float d2 = __fadd_rn(__fadd_rn(__fmul_rn(dx,dx), __fmul_rn(dy,dy)), __fmul_rn(dz,dz));
      bool ok = (j != i) && (d2 <= T);
      if (ok) {
        int p2 = atomicAdd(&cntL[wv], 1);
        if (p2 < 128) { d2b[wv][p2] = d2; jb[wv][p2] = j; }
      }
    }
    int cnt = cntL[wv];
    if (cnt > 128) cnt = 128;

    for (int s = lane; s < cnt; s += 64) {
      float dm = d2b[wv][s]; int jm = jb[wv][s];
      int rank = 0;
      for (int c = 0; c < cnt; ++c) {
        float dc = d2b[wv][c]; int jc = jb[wv][c];
        if (dc < dm || (dc == dm && jc < jm)) ++rank;
      }
      if (rank < KNN) {
        size_t base = ((size_t)b * NNODE + i) * KNN;
        eidx[base + rank]  = b * NNODE + jm;
        edist[base + rank] = sqrtf(__fadd_rn(dm, 1e-8f));
      }
    }
  }
}

// ---------------------------------------------------------------------------
// Kernel 2: edge MLP + mask + aggregate.
// 512-thread/8-wave blocks = 2 waves/SIMD (VGPR ~190 < 256 cap, no spill),
// ILP-2, single reused m1 buffer per wave (write A -> read A-frags ->
// overwrite with B -> read B-frags; same-wave DS ordering keeps it safe).
// ---------------------------------------------------------------------------
#define ENPW 16

__global__ __launch_bounds__(512)
void edge_kernel(const float* __restrict__ h,
                 const int* __restrict__ eidx, const float* __restrict__ edist,
                 const float* __restrict__ ew1, const float* __restrict__ eb1,
                 const float* __restrict__ ew2, const float* __restrict__ eb2,
                 float* __restrict__ agg)
{
  __shared__ __attribute__((aligned(16))) short8 F1[9*8*64];   // 73,728 B
  __shared__ __attribute__((aligned(16))) short8 F2[4*8*64];   // 32,768 B
  __shared__ __attribute__((aligned(16))) short m1s[8][2048];  // 32,768 B

  const int tid = threadIdx.x;
  for (int f = tid; f < 9*8*64; f += 512) {
    int kc = f >> 9, rem = f & 511, nf = rem >> 6, ln = rem & 63;
    int kb = kc*32 + (ln >> 4)*8, col = nf*16 + (ln & 15);
    short8 v;
    #pragma unroll
    for (int e = 0; e < 8; ++e) {
      int k = kb + e;
      v[e] = (k < 276) ? f2bf(ew1[k*128 + col]) : (short)0;
    }
    F1[f] = v;
  }
  for (int f = tid; f < 4*8*64; f += 512) {
    int kc = f >> 9, rem = f & 511, nf = rem >> 6, ln = rem & 63;
    int kb = kc*32 + (ln >> 4)*8, col = nf*16 + (ln & 15);
    short8 v;
    #pragma unroll
    for (int e = 0; e < 8; ++e) v[e] = f2bf(ew2[(kb + e)*128 + col]);
    F2[f] = v;
  }
  __syncthreads();

  const int wv = tid >> 6, lane = tid & 63;
  const int lo = lane & 15, hi = lane >> 4;
  short* m1w = &m1s[wv][0];

  float b1v[8], b2v[8];
  #pragma unroll
  for (int nf = 0; nf < 8; ++nf) {
    b1v[nf] = eb1[nf*16 + lo];
    b2v[nf] = eb2[nf*16 + lo];
  }
  int wbase[4], xmask[4], rbase[4];
  #pragma unroll
  for (int q = 0; q < 4; ++q) {
    int row = hi*4 + q;
    wbase[q] = (row << 8) + (lo << 1);
    xmask[q] = (row & 7) << 4;
  }
  #pragma unroll
  for (int kc = 0; kc < 4; ++kc)
    rbase[kc] = ((lo << 8) + ((kc*32 + hi*8) << 1)) ^ ((lo & 7) << 4);

  const f32x4 zero4 = {0.f, 0.f, 0.f, 0.f};
  const int nbase = (blockIdx.x * 8 + wv) * ENPW;

  #pragma unroll 1
  for (int it = 0; it < ENPW/2; ++it) {
    const int nA = nbase + it*2, nB = nA + 1;
    int jgA = eidx[(size_t)nA*KNN + lo] & (NBATCH*NNODE - 1);
    int jgB = eidx[(size_t)nB*KNN + lo] & (NBATCH*NNODE - 1);
    const float deA = edist[(size_t)nA*KNN + lo];
    const float deB = edist[(size_t)nB*KNN + lo];

    short8 aIA[4], aJA[4], aIB[4], aJB[4];
    #pragma unroll
    for (int kc = 0; kc < 4; ++kc) {
      aIA[kc] = cv8(h + (size_t)nA*HID  + kc*32 + hi*8);
      aJA[kc] = cv8(h + (size_t)jgA*HID + kc*32 + hi*8);
      aIB[kc] = cv8(h + (size_t)nB*HID  + kc*32 + hi*8);
      aJB[kc] = cv8(h + (size_t)jgB*HID + kc*32 + hi*8);
    }
    short8 aRA, aRB;
    #pragma unroll
    for (int e = 0; e < 8; ++e) {
      const int r = hi*8 + e;
      float vA = 0.f, vB = 0.f;
      if (r < NRBF) {
        const float cr = (float)(r * (5.0/19.0));
        float tA = __fsub_rn(deA, cr), tB = __fsub_rn(deB, cr);
        vA = __expf(-16.0f * __fmul_rn(tA, tA));
        vB = __expf(-16.0f * __fmul_rn(tB, tB));
      }
      aRA[e] = f2bf(vA); aRB[e] = f2bf(vB);
    }

    f32x4 acc1A[8], acc1B[8];
    #pragma unroll
    for (int nf = 0; nf < 8; ++nf) { acc1A[nf] = zero4; acc1B[nf] = zero4; }
    #pragma unroll
    for (int kc = 0; kc < 9; ++kc) {
      short8 aA = (kc < 4) ? aIA[kc] : ((kc < 8) ? aJA[kc-4] : aRA);
      short8 aB = (kc < 4) ? aIB[kc] : ((kc < 8) ? aJB[kc-4] : aRB);
      #pragma unroll
      for (int nf = 0; nf < 8; ++nf) {
        short8 bf = F1[(kc*8 + nf)*64 + lane];     // one read feeds 2 MFMAs
        acc1A[nf] = __builtin_amdgcn_mfma_f32_16x16x32_bf16(aA, bf, acc1A[nf], 0,0,0);
        acc1B[nf] = __builtin_amdgcn_mfma_f32_16x16x32_bf16(aB, bf, acc1B[nf], 0,0,0);
      }
    }

    // m1 transpose through ONE per-wave buffer: A write -> A frag read ->
    // B write (same addrs) -> B frag read. Same-wave DS ops are ordered.
    short8 a2A[4], a2B[4];
    #pragma unroll
    for (int nf = 0; nf < 8; ++nf) {
      #pragma unroll
      for (int q = 0; q < 4; ++q) {
        int off = (wbase[q] + (nf << 5)) ^ xmask[q];
        *(short*)((char*)m1w + off) = f2bf(silu_f(acc1A[nf][q] + b1v[nf]));
      }
    }
    #pragma unroll
    for (int kc = 0; kc < 4; ++kc)
      a2A[kc] = *(const short8*)((char*)m1w + rbase[kc]);
    #pragma unroll
    for (int nf = 0; nf < 8; ++nf) {
      #pragma unroll
      for (int q = 0; q < 4; ++q) {
        int off = (wbase[q] + (nf << 5)) ^ xmask[q];
        *(short*)((char*)m1w + off) = f2bf(silu_f(acc1B[nf][q] + b1v[nf]));
      }
    }
    #pragma unroll
    for (int kc = 0; kc < 4; ++kc)
      a2B[kc] = *(const short8*)((char*)m1w + rbase[kc]);

    f32x4 acc2A[8], acc2B[8];
    #pragma unroll
    for (int nf = 0; nf < 8; ++nf) { acc2A[nf] = zero4; acc2B[nf] = zero4; }
    #pragma unroll
    for (int kc = 0; kc < 4; ++kc) {
      #pragma unroll
      for (int nf = 0; nf < 8; ++nf) {
        short8 bf = F2[(kc*8 + nf)*64 + lane];
        acc2A[nf] = __builtin_amdgcn_mfma_f32_16x16x32_bf16(a2A[kc], bf, acc2A[nf], 0,0,0);
        acc2B[nf] = __builtin_amdgcn_mfma_f32_16x16x32_bf16(a2B[kc], bf, acc2B[nf], 0,0,0);
      }
    }

    float dqA[4], dqB[4];
    #pragma unroll
    for (int q = 0; q < 4; ++q) {
      dqA[q] = edist[(size_t)nA*KNN + hi*4 + q];
      dqB[q] = edist[(size_t)nB*KNN + hi*4 + q];
    }
    #pragma unroll
    for (int nf = 0; nf < 8; ++nf) {
      float sA = 0.f, sB = 0.f;
      #pragma unroll
      for (int q = 0; q < 4; ++q) {
        float mA = silu_f(acc2A[nf][q] + b2v[nf]);
        float mB = silu_f(acc2B[nf][q] + b2v[nf]);
        sA += (dqA[q] < 5.0f) ? mA : 0.f;
        sB += (dqB[q] < 5.0f) ? mB : 0.f;
      }
      sA += __shfl_xor(sA, 16); sA += __shfl_xor(sA, 32);
      sB += __shfl_xor(sB, 16); sB += __shfl_xor(sB, 32);
      if (hi == 0) {
        agg[(size_t)nA*HID + nf*16 + lo] = sA;
        agg[(size_t)nB*HID + nf*16 + lo] = sB;
      }
    }
  }
}

// ---------------------------------------------------------------------------
// Kernel 3: node MLP + residual + LayerNorm, f32 I/O, agg==out in-place.
// 512-thread/8-wave blocks, fragment-linear weight LDS (131 KB).
// ---------------------------------------------------------------------------
__global__ __launch_bounds__(512)
void node_kernel(const float* __restrict__ h, const float* agg,
                 const float* __restrict__ nw1, const float* __restrict__ nb1,
                 const float* __restrict__ nw2, const float* __restrict__ nb2,
                 const float* __restrict__ gam, const float* __restrict__ bet,
                 float* out)
{
  __shared__ __attribute__((aligned(16))) short8 G1[8*8*64];   // 65,536 B
  __shared__ __attribute__((aligned(16))) short8 G2[4*8*64];   // 32,768 B
  __shared__ __attribute__((aligned(16))) short m1s[8][2048];  // 32,768 B

  const int tid = threadIdx.x;
  for (int f = tid; f < 8*8*64; f += 512) {
    int kc = f >> 9, rem = f & 511, nf = rem >> 6, ln = rem & 63;
    int kb = kc*32 + (ln >> 4)*8, col = nf*16 + (ln & 15);
    short8 v;
    #pragma unroll
    for (int e = 0; e < 8; ++e) v[e] = f2bf(nw1[(kb + e)*128 + col]);
    G1[f] = v;
  }
  for (int f = tid; f < 4*8*64; f += 512) {
    int kc = f >> 9, rem = f & 511, nf = rem >> 6, ln = rem & 63;
    int kb = kc*32 + (ln >> 4)*8, col = nf*16 + (ln & 15);
    short8 v;
    #pragma unroll
    for (int e = 0; e < 8; ++e) v[e] = f2bf(nw2[(kb + e)*128 + col]);
    G2[f] = v;
  }
  __syncthreads();

  const int wv = tid >> 6, lane = tid & 63;
  const int lo = lane & 15, hi = lane >> 4;
  short* m1w = &m1s[wv][0];

  float b1v[8], b2v[8], gv[8], bv[8];
  #pragma unroll
  for (int nf = 0; nf < 8; ++nf) {
    b1v[nf] = nb1[nf*16 + lo];
    b2v[nf] = nb2[nf*16 + lo];
    gv[nf]  = gam[nf*16 + lo];
    bv[nf]  = bet[nf*16 + lo];
  }
  const f32x4 zero4 = {0.f, 0.f, 0.f, 0.f};

  const int row0 = (blockIdx.x * 8 + wv) * 16;

  const float* hrow = h   + (size_t)(row0 + lo) * HID;
  const float* arow = agg + (size_t)(row0 + lo) * HID;

  f32x4 acc1[8];
  #pragma unroll
  for (int nf = 0; nf < 8; ++nf) acc1[nf] = zero4;
  #pragma unroll
  for (int kc = 0; kc < 8; ++kc) {
    short8 a = (kc < 4) ? cv8(hrow + kc*32 + hi*8)
                        : cv8(arow + (kc - 4)*32 + hi*8);
    #pragma unroll
    for (int nf = 0; nf < 8; ++nf) {
      short8 bf = G1[(kc*8 + nf)*64 + lane];
      acc1[nf] = __builtin_amdgcn_mfma_f32_16x16x32_bf16(a, bf, acc1[nf], 0,0,0);
    }
  }

  #pragma unroll
  for (int nf = 0; nf < 8; ++nf) {
    #pragma unroll
    for (int q = 0; q < 4; ++q) {
      float s = silu_f(acc1[nf][q] + b1v[nf]);
      int row = hi*4 + q, col = nf*16 + lo;
      int byteoff = ((row << 8) + (col << 1)) ^ ((row & 7) << 4);
      *(short*)((char*)m1w + byteoff) = f2bf(s);
    }
  }

  f32x4 acc2[8];
  #pragma unroll
  for (int nf = 0; nf < 8; ++nf) acc2[nf] = zero4;
  #pragma unroll
  for (int kc = 0; kc < 4; ++kc) {
    int byteA = ((lo << 8) + ((kc*32 + hi*8) << 1)) ^ ((lo & 7) << 4);
    short8 a = *(const short8*)((char*)m1w + byteA);
    #pragma unroll
    for (int nf = 0; nf < 8; ++nf) {
      short8 bf = G2[(kc*8 + nf)*64 + lane];
      acc2[nf] = __builtin_amdgcn_mfma_f32_16x16x32_bf16(a, bf, acc2[nf], 0,0,0);
    }
  }

  float xv[4][8];
  #pragma unroll
  for (int nf = 0; nf < 8; ++nf) {
    #pragma unroll
    for (int q = 0; q < 4; ++q) {
      xv[q][nf] = acc2[nf][q] + b2v[nf]
                + h[(size_t)(row0 + hi*4 + q) * HID + nf*16 + lo];
    }
  }

  #pragma unroll
  for (int q = 0; q < 4; ++q) {
    float s = 0.0f;
    #pragma unroll
    for (int nf = 0; nf < 8; ++nf) s += xv[q][nf];
    s += __shfl_xor(s, 1); s += __shfl_xor(s, 2);
    s += __shfl_xor(s, 4); s += __shfl_xor(s, 8);
    float mu = s * 0.0078125f;
    float t = 0.0f;
    #pragma unroll
    for (int nf = 0; nf < 8; ++nf) { float d = xv[q][nf] - mu; t += d * d; }
    t += __shfl_xor(t, 1); t += __shfl_xor(t, 2);
    t += __shfl_xor(t, 4); t += __shfl_xor(t, 8);
    float inv = 1.0f / sqrtf(t * 0.0078125f + 1e-5f);
    #pragma unroll
    for (int nf = 0; nf < 8; ++nf) {
      float y = (xv[q][nf] - mu) * inv * gv[nf] + bv[nf];
      out[(size_t)(row0 + hi*4 + q) * HID + nf*16 + lo] = y;
    }
  }
}

// ---------------------------------------------------------------------------
extern "C" void kernel_launch(void* const* d_in, const int* in_sizes, int n_in,
                              void* d_out, int out_size, void* d_ws, size_t ws_size,
                              hipStream_t stream) {
  (void)in_sizes; (void)n_in; (void)out_size;
  const float* h   = (const float*)d_in[0];
  const float* pos = (const float*)d_in[1];
  const float* ew1 = (const float*)d_in[2];
  const float* eb1 = (const float*)d_in[3];
  const float* ew2 = (const float*)d_in[4];
  const float* eb2 = (const float*)d_in[5];
  const float* nw1 = (const float*)d_in[6];
  const float* nb1 = (const float*)d_in[7];
  const float* nw2 = (const float*)d_in[8];
  const float* nb2 = (const float*)d_in[9];
  const float* gam = (const float*)d_in[10];
  const float* bet = (const float*)d_in[11];

  const size_t need = (size_t)NBATCH * NNODE * KNN * 8;   // 4 MB
  if (ws_size < need) return;

  char* wsp = (char*)d_ws;
  int*   eidx  = (int*)wsp;
  float* edist = (float*)(wsp + (size_t)NBATCH * NNODE * KNN * 4);
  float* agg   = (float*)d_out;

  knn_kernel<<<dim3(1024), dim3(512), 0, stream>>>(pos, eidx, edist);
  edge_kernel<<<dim3(256), dim3(512), 0, stream>>>(h, eidx, edist, ew1, eb1, ew2, eb2, agg);
  node_kernel<<<dim3(256), dim3(512), 0, stream>>>(h, agg, nw1, nb1, nw2, nb2, gam, bet,
                                                   (float*)d_out);
}

// Round 8
// 211.713 us; speedup vs baseline: 2.8441x; 1.1207x over previous
//
#include <hip/hip_runtime.h>

#define HID 128
#define NRBF 20
#define KNN 16
#define NNODE 4096
#define NBATCH 8
#define CAP 112

typedef __attribute__((ext_vector_type(8))) short short8;
typedef __attribute__((ext_vector_type(4))) float f32x4;

// branchless RNE f32->bf16 (4 int VALU ops; inputs are finite here)
__device__ __forceinline__ short f2bf(float x) {
  unsigned u = __builtin_bit_cast(unsigned, x);
  u = u + 0x7FFFu + ((u >> 16) & 1u);
  return (short)(u >> 16);
}
__device__ __forceinline__ float silu_f(float x) {
  return x * __builtin_amdgcn_rcpf(1.0f + __expf(-x));  // ~1e-7 rel err << bf16 rounding
}
__device__ __forceinline__ short8 cv8(const float* p) {
  f32x4 a = *(const f32x4*)p;
  f32x4 b = *(const f32x4*)(p + 4);
  short8 r;
  r[0]=f2bf(a[0]); r[1]=f2bf(a[1]); r[2]=f2bf(a[2]); r[3]=f2bf(a[3]);
  r[4]=f2bf(b[0]); r[5]=f2bf(b[1]); r[6]=f2bf(b[2]); r[7]=f2bf(b[3]);
  return r;
}

// ---------------------------------------------------------------------------
// Kernel 0: h (f32) -> hb (bf16), once. 4.19M elems, BW-bound (~5 us).
// ---------------------------------------------------------------------------
__global__ __launch_bounds__(256)
void hcvt_kernel(const float* __restrict__ h, short* __restrict__ hb)
{
  size_t i = ((size_t)blockIdx.x * 256 + threadIdx.x) * 8;
  *(short8*)(hb + i) = cv8(h + i);
}

// ---------------------------------------------------------------------------
// Kernel 1: exact kNN (top-16, stable index tiebreak), f32.
// Pass-1: batched strip minima, self INCLUDED (d2=0) -> threshold = element 16
// of the bitonic-sorted 64 minima (still provably >= true 16th distance:
// v[0..16] holds 17 actual distances of distinct candidates, at most 1 self).
// Pass-2: single batched scan, 4 compact buffers. Arithmetic bit-exact numpy.
// ---------------------------------------------------------------------------
__global__ __launch_bounds__(512)
void knn_kernel(const float* __restrict__ pos,
                int* __restrict__ eidx, float* __restrict__ edist)
{
  __shared__ float pX[NNODE], pY[NNODE], pZ[NNODE];   // 48 KB
  __shared__ float d2b[8][4][CAP];                    // 14 KB
  __shared__ int   jb[8][4][CAP];                     // 14 KB
  __shared__ int   cntL[8][4];

  const int tid  = threadIdx.x;
  const int wv   = tid >> 6;
  const int lane = tid & 63;
  const int b    = blockIdx.x >> 7;
  const int grp  = blockIdx.x & 127;

  const float* pb = pos + (size_t)b * NNODE * 3;
  for (int idx = tid; idx < NNODE; idx += 512) {
    pX[idx] = pb[idx*3]; pY[idx] = pb[idx*3+1]; pZ[idx] = pb[idx*3+2];
  }
  __syncthreads();

  const int i0 = grp * 32 + wv * 4;
  float pix[4], piy[4], piz[4];
  #pragma unroll
  for (int n = 0; n < 4; ++n) { pix[n]=pX[i0+n]; piy[n]=pY[i0+n]; piz[n]=pZ[i0+n]; }

  // pass 1: per-lane strip minima for 4 nodes (self included, d2=0 exact)
  float vmin[4] = {3.0e38f, 3.0e38f, 3.0e38f, 3.0e38f};
  #pragma unroll 4
  for (int t = 0; t < 64; ++t) {
    const int j = t * 64 + lane;
    const float x = pX[j], y = pY[j], z = pZ[j];
    #pragma unroll
    for (int n = 0; n < 4; ++n) {
      float dx = __fsub_rn(pix[n], x);
      float dy = __fsub_rn(piy[n], y);
      float dz = __fsub_rn(piz[n], z);
      float d2 = __fadd_rn(__fadd_rn(__fmul_rn(dx,dx), __fmul_rn(dy,dy)), __fmul_rn(dz,dz));
      vmin[n] = fminf(vmin[n], d2);
    }
  }

  float Ts[4];
  #pragma unroll
  for (int n = 0; n < 4; ++n) {
    float v = vmin[n];
    #pragma unroll
    for (int k = 2; k <= 64; k <<= 1) {
      #pragma unroll
      for (int jj = k >> 1; jj > 0; jj >>= 1) {
        float o = __shfl_xor(v, jj);
        const bool up   = ((lane & k) == 0);
        const bool lowl = ((lane & jj) == 0);
        float mn = fminf(v, o), mx = fmaxf(v, o);
        v = (up == lowl) ? mn : mx;
      }
    }
    Ts[n] = __shfl(v, 16);   // element 16: >= true 16th non-self distance
  }

  if (lane < 4) cntL[wv][lane] = 0;
  // pass 2: ONE batched scan, compact per node (j != i excluded here)
  #pragma unroll 2
  for (int t = 0; t < 64; ++t) {
    const int j = t * 64 + lane;
    const float x = pX[j], y = pY[j], z = pZ[j];
    #pragma unroll
    for (int n = 0; n < 4; ++n) {
      float dx = __fsub_rn(pix[n], x);
      float dy = __fsub_rn(piy[n], y);
      float dz = __fsub_rn(piz[n], z);
      float d2 = __fadd_rn(__fadd_rn(__fmul_rn(dx,dx), __fmul_rn(dy,dy)), __fmul_rn(dz,dz));
      if ((j != i0 + n) && (d2 <= Ts[n])) {
        int p = atomicAdd(&cntL[wv][n], 1);
        if (p < CAP) { d2b[wv][n][p] = d2; jb[wv][n][p] = j; }
      }
    }
  }

  // exact stable rank selection per node
  #pragma unroll 1
  for (int n = 0; n < 4; ++n) {
    int cnt = cntL[wv][n];
    if (cnt > CAP) cnt = CAP;
    for (int s = lane; s < cnt; s += 64) {
      float dm = d2b[wv][n][s]; int jm = jb[wv][n][s];
      int rank = 0;
      for (int c = 0; c < cnt; ++c) {
        float dc = d2b[wv][n][c]; int jc = jb[wv][n][c];
        if (dc < dm || (dc == dm && jc < jm)) ++rank;
      }
      if (rank < KNN) {
        size_t base = ((size_t)b * NNODE + i0 + n) * KNN;
        eidx[base + rank]  = b * NNODE + jm;
        edist[base + rank] = sqrtf(__fadd_rn(dm, 1e-8f));
      }
    }
  }
}

// ---------------------------------------------------------------------------
// Kernel 2: edge MLP + mask + aggregate. 8 waves/block, ILP-2,
// fragment-linear weight LDS, HBF: gather pre-converted bf16 h (no cvt VALU).
// ---------------------------------------------------------------------------
#define ENPW 16

template<bool HBF>
__global__ __launch_bounds__(512)
void edge_kernel(const float* __restrict__ h, const short* __restrict__ hb,
                 const int* __restrict__ eidx, const float* __restrict__ edist,
                 const float* __restrict__ ew1, const float* __restrict__ eb1,
                 const float* __restrict__ ew2, const float* __restrict__ eb2,
                 float* __restrict__ agg)
{
  __shared__ __attribute__((aligned(16))) short8 F1[9*8*64];   // 73,728 B
  __shared__ __attribute__((aligned(16))) short8 F2[4*8*64];   // 32,768 B
  __shared__ __attribute__((aligned(16))) short m1s[8][2048];  // 32,768 B

  const int tid = threadIdx.x;
  for (int f = tid; f < 9*8*64; f += 512) {
    int kc = f >> 9, rem = f & 511, nf = rem >> 6, ln = rem & 63;
    int kb = kc*32 + (ln >> 4)*8, col = nf*16 + (ln & 15);
    short8 v;
    #pragma unroll
    for (int e = 0; e < 8; ++e) {
      int k = kb + e;
      v[e] = (k < 276) ? f2bf(ew1[k*128 + col]) : (short)0;
    }
    F1[f] = v;
  }
  for (int f = tid; f < 4*8*64; f += 512) {
    int kc = f >> 9, rem = f & 511, nf = rem >> 6, ln = rem & 63;
    int kb = kc*32 + (ln >> 4)*8, col = nf*16 + (ln & 15);
    short8 v;
    #pragma unroll
    for (int e = 0; e < 8; ++e) v[e] = f2bf(ew2[(kb + e)*128 + col]);
    F2[f] = v;
  }
  __syncthreads();

  const int wv = tid >> 6, lane = tid & 63;
  const int lo = lane & 15, hi = lane >> 4;
  short* m1w = &m1s[wv][0];

  float b1v[8], b2v[8];
  #pragma unroll
  for (int nf = 0; nf < 8; ++nf) {
    b1v[nf] = eb1[nf*16 + lo];
    b2v[nf] = eb2[nf*16 + lo];
  }
  int wbase[4], xmask[4], rbase[4];
  #pragma unroll
  for (int q = 0; q < 4; ++q) {
    int row = hi*4 + q;
    wbase[q] = (row << 8) + (lo << 1);
    xmask[q] = (row & 7) << 4;
  }
  #pragma unroll
  for (int kc = 0; kc < 4; ++kc)
    rbase[kc] = ((lo << 8) + ((kc*32 + hi*8) << 1)) ^ ((lo & 7) << 4);

  const f32x4 zero4 = {0.f, 0.f, 0.f, 0.f};
  const int nbase = (blockIdx.x * 8 + wv) * ENPW;

  #pragma unroll 1
  for (int it = 0; it < ENPW/2; ++it) {
    const int nA = nbase + it*2, nB = nA + 1;
    int jgA = eidx[(size_t)nA*KNN + lo] & (NBATCH*NNODE - 1);
    int jgB = eidx[(size_t)nB*KNN + lo] & (NBATCH*NNODE - 1);
    const float deA = edist[(size_t)nA*KNN + lo];
    const float deB = edist[(size_t)nB*KNN + lo];

    short8 aIA[4], aJA[4], aIB[4], aJB[4];
    #pragma unroll
    for (int kc = 0; kc < 4; ++kc) {
      if constexpr (HBF) {
        aIA[kc] = *(const short8*)(hb + (size_t)nA*HID  + kc*32 + hi*8);
        aJA[kc] = *(const short8*)(hb + (size_t)jgA*HID + kc*32 + hi*8);
        aIB[kc] = *(const short8*)(hb + (size_t)nB*HID  + kc*32 + hi*8);
        aJB[kc] = *(const short8*)(hb + (size_t)jgB*HID + kc*32 + hi*8);
      } else {
        aIA[kc] = cv8(h + (size_t)nA*HID  + kc*32 + hi*8);
        aJA[kc] = cv8(h + (size_t)jgA*HID + kc*32 + hi*8);
        aIB[kc] = cv8(h + (size_t)nB*HID  + kc*32 + hi*8);
        aJB[kc] = cv8(h + (size_t)jgB*HID + kc*32 + hi*8);
      }
    }
    short8 aRA, aRB;
    #pragma unroll
    for (int e = 0; e < 8; ++e) {
      const int r = hi*8 + e;
      float vA = 0.f, vB = 0.f;
      if (r < NRBF) {
        const float cr = (float)(r * (5.0/19.0));
        float tA = __fsub_rn(deA, cr), tB = __fsub_rn(deB, cr);
        vA = __expf(-16.0f * __fmul_rn(tA, tA));
        vB = __expf(-16.0f * __fmul_rn(tB, tB));
      }
      aRA[e] = f2bf(vA); aRB[e] = f2bf(vB);
    }

    f32x4 acc1A[8], acc1B[8];
    #pragma unroll
    for (int nf = 0; nf < 8; ++nf) { acc1A[nf] = zero4; acc1B[nf] = zero4; }
    __builtin_amdgcn_s_setprio(1);
    #pragma unroll
    for (int kc = 0; kc < 9; ++kc) {
      short8 aA = (kc < 4) ? aIA[kc] : ((kc < 8) ? aJA[kc-4] : aRA);
      short8 aB = (kc < 4) ? aIB[kc] : ((kc < 8) ? aJB[kc-4] : aRB);
      #pragma unroll
      for (int nf = 0; nf < 8; ++nf) {
        short8 bf = F1[(kc*8 + nf)*64 + lane];     // one read feeds 2 MFMAs
        acc1A[nf] = __builtin_amdgcn_mfma_f32_16x16x32_bf16(aA, bf, acc1A[nf], 0,0,0);
        acc1B[nf] = __builtin_amdgcn_mfma_f32_16x16x32_bf16(aB, bf, acc1B[nf], 0,0,0);
      }
    }
    __builtin_amdgcn_s_setprio(0);

    // m1 transpose through ONE per-wave buffer (same-wave DS ordering)
    short8 a2A[4], a2B[4];
    #pragma unroll
    for (int nf = 0; nf < 8; ++nf) {
      #pragma unroll
      for (int q = 0; q < 4; ++q) {
        int off = (wbase[q] + (nf << 5)) ^ xmask[q];
        *(short*)((char*)m1w + off) = f2bf(silu_f(acc1A[nf][q] + b1v[nf]));
      }
    }
    #pragma unroll
    for (int kc = 0; kc < 4; ++kc)
      a2A[kc] = *(const short8*)((char*)m1w + rbase[kc]);
    #pragma unroll
    for (int nf = 0; nf < 8; ++nf) {
      #pragma unroll
      for (int q = 0; q < 4; ++q) {
        int off = (wbase[q] + (nf << 5)) ^ xmask[q];
        *(short*)((char*)m1w + off) = f2bf(silu_f(acc1B[nf][q] + b1v[nf]));
      }
    }
    #pragma unroll
    for (int kc = 0; kc < 4; ++kc)
      a2B[kc] = *(const short8*)((char*)m1w + rbase[kc]);

    f32x4 acc2A[8], acc2B[8];
    #pragma unroll
    for (int nf = 0; nf < 8; ++nf) { acc2A[nf] = zero4; acc2B[nf] = zero4; }
    __builtin_amdgcn_s_setprio(1);
    #pragma unroll
    for (int kc = 0; kc < 4; ++kc) {
      #pragma unroll
      for (int nf = 0; nf < 8; ++nf) {
        short8 bf = F2[(kc*8 + nf)*64 + lane];
        acc2A[nf] = __builtin_amdgcn_mfma_f32_16x16x32_bf16(a2A[kc], bf, acc2A[nf], 0,0,0);
        acc2B[nf] = __builtin_amdgcn_mfma_f32_16x16x32_bf16(a2B[kc], bf, acc2B[nf], 0,0,0);
      }
    }
    __builtin_amdgcn_s_setprio(0);

    float dqA[4], dqB[4];
    #pragma unroll
    for (int q = 0; q < 4; ++q) {
      dqA[q] = edist[(size_t)nA*KNN + hi*4 + q];
      dqB[q] = edist[(size_t)nB*KNN + hi*4 + q];
    }
    #pragma unroll
    for (int nf = 0; nf < 8; ++nf) {
      float sA = 0.f, sB = 0.f;
      #pragma unroll
      for (int q = 0; q < 4; ++q) {
        float mA = silu_f(acc2A[nf][q] + b2v[nf]);
        float mB = silu_f(acc2B[nf][q] + b2v[nf]);
        sA += (dqA[q] < 5.0f) ? mA : 0.f;
        sB += (dqB[q] < 5.0f) ? mB : 0.f;
      }
      sA += __shfl_xor(sA, 16); sA += __shfl_xor(sA, 32);
      sB += __shfl_xor(sB, 16); sB += __shfl_xor(sB, 32);
      if (hi == 0) {
        agg[(size_t)nA*HID + nf*16 + lo] = sA;
        agg[(size_t)nB*HID + nf*16 + lo] = sB;
      }
    }
  }
}

// ---------------------------------------------------------------------------
// Kernel 3: node MLP + residual + LayerNorm, agg==out in-place, 8-wave blocks.
// ---------------------------------------------------------------------------
template<bool HBF>
__global__ __launch_bounds__(512)
void node_kernel(const float* __restrict__ h, const short* __restrict__ hb,
                 const float* agg,
                 const float* __restrict__ nw1, const float* __restrict__ nb1,
                 const float* __restrict__ nw2, const float* __restrict__ nb2,
                 const float* __restrict__ gam, const float* __restrict__ bet,
                 float* out)
{
  __shared__ __attribute__((aligned(16))) short8 G1[8*8*64];   // 65,536 B
  __shared__ __attribute__((aligned(16))) short8 G2[4*8*64];   // 32,768 B
  __shared__ __attribute__((aligned(16))) short m1s[8][2048];  // 32,768 B

  const int tid = threadIdx.x;
  for (int f = tid; f < 8*8*64; f += 512) {
    int kc = f >> 9, rem = f & 511, nf = rem >> 6, ln = rem & 63;
    int kb = kc*32 + (ln >> 4)*8, col = nf*16 + (ln & 15);
    short8 v;
    #pragma unroll
    for (int e = 0; e < 8; ++e) v[e] = f2bf(nw1[(kb + e)*128 + col]);
    G1[f] = v;
  }
  for (int f = tid; f < 4*8*64; f += 512) {
    int kc = f >> 9, rem = f & 511, nf = rem >> 6, ln = rem & 63;
    int kb = kc*32 + (ln >> 4)*8, col = nf*16 + (ln & 15);
    short8 v;
    #pragma unroll
    for (int e = 0; e < 8; ++e) v[e] = f2bf(nw2[(kb + e)*128 + col]);
    G2[f] = v;
  }
  __syncthreads();

  const int wv = tid >> 6, lane = tid & 63;
  const int lo = lane & 15, hi = lane >> 4;
  short* m1w = &m1s[wv][0];

  float b1v[8], b2v[8], gv[8], bv[8];
  #pragma unroll
  for (int nf = 0; nf < 8; ++nf) {
    b1v[nf] = nb1[nf*16 + lo];
    b2v[nf] = nb2[nf*16 + lo];
    gv[nf]  = gam[nf*16 + lo];
    bv[nf]  = bet[nf*16 + lo];
  }
  const f32x4 zero4 = {0.f, 0.f, 0.f, 0.f};

  const int row0 = (blockIdx.x * 8 + wv) * 16;

  const float* hrow = h   + (size_t)(row0 + lo) * HID;
  const float* arow = agg + (size_t)(row0 + lo) * HID;
  const short* hbrow = hb + (size_t)(row0 + lo) * HID;

  f32x4 acc1[8];
  #pragma unroll
  for (int nf = 0; nf < 8; ++nf) acc1[nf] = zero4;
  #pragma unroll
  for (int kc = 0; kc < 8; ++kc) {
    short8 a;
    if (kc < 4) {
      if constexpr (HBF) a = *(const short8*)(hbrow + kc*32 + hi*8);
      else               a = cv8(hrow + kc*32 + hi*8);
    } else {
      a = cv8(arow + (kc - 4)*32 + hi*8);
    }
    #pragma unroll
    for (int nf = 0; nf < 8; ++nf) {
      short8 bf = G1[(kc*8 + nf)*64 + lane];
      acc1[nf] = __builtin_amdgcn_mfma_f32_16x16x32_bf16(a, bf, acc1[nf], 0,0,0);
    }
  }

  #pragma unroll
  for (int nf = 0; nf < 8; ++nf) {
    #pragma unroll
    for (int q = 0; q < 4; ++q) {
      float s = silu_f(acc1[nf][q] + b1v[nf]);
      int row = hi*4 + q, col = nf*16 + lo;
      int byteoff = ((row << 8) + (col << 1)) ^ ((row & 7) << 4);
      *(short*)((char*)m1w + byteoff) = f2bf(s);
    }
  }

  f32x4 acc2[8];
  #pragma unroll
  for (int nf = 0; nf < 8; ++nf) acc2[nf] = zero4;
  #pragma unroll
  for (int kc = 0; kc < 4; ++kc) {
    int byteA = ((lo << 8) + ((kc*32 + hi*8) << 1)) ^ ((lo & 7) << 4);
    short8 a = *(const short8*)((char*)m1w + byteA);
    #pragma unroll
    for (int nf = 0; nf < 8; ++nf) {
      short8 bf = G2[(kc*8 + nf)*64 + lane];
      acc2[nf] = __builtin_amdgcn_mfma_f32_16x16x32_bf16(a, bf, acc2[nf], 0,0,0);
    }
  }

  float xv[4][8];
  #pragma unroll
  for (int nf = 0; nf < 8; ++nf) {
    #pragma unroll
    for (int q = 0; q < 4; ++q) {
      xv[q][nf] = acc2[nf][q] + b2v[nf]
                + h[(size_t)(row0 + hi*4 + q) * HID + nf*16 + lo];
    }
  }

  #pragma unroll
  for (int q = 0; q < 4; ++q) {
    float s = 0.0f;
    #pragma unroll
    for (int nf = 0; nf < 8; ++nf) s += xv[q][nf];
    s += __shfl_xor(s, 1); s += __shfl_xor(s, 2);
    s += __shfl_xor(s, 4); s += __shfl_xor(s, 8);
    float mu = s * 0.0078125f;
    float t = 0.0f;
    #pragma unroll
    for (int nf = 0; nf < 8; ++nf) { float d = xv[q][nf] - mu; t += d * d; }
    t += __shfl_xor(t, 1); t += __shfl_xor(t, 2);
    t += __shfl_xor(t, 4); t += __shfl_xor(t, 8);
    float inv = 1.0f / sqrtf(t * 0.0078125f + 1e-5f);
    #pragma unroll
    for (int nf = 0; nf < 8; ++nf) {
      float y = (xv[q][nf] - mu) * inv * gv[nf] + bv[nf];
      out[(size_t)(row0 + hi*4 + q) * HID + nf*16 + lo] = y;
    }
  }
}

// ---------------------------------------------------------------------------
extern "C" void kernel_launch(void* const* d_in, const int* in_sizes, int n_in,
                              void* d_out, int out_size, void* d_ws, size_t ws_size,
                              hipStream_t stream) {
  (void)in_sizes; (void)n_in; (void)out_size;
  const float* h   = (const float*)d_in[0];
  const float* pos = (const float*)d_in[1];
  const float* ew1 = (const float*)d_in[2];
  const float* eb1 = (const float*)d_in[3];
  const float* ew2 = (const float*)d_in[4];
  const float* eb2 = (const float*)d_in[5];
  const float* nw1 = (const float*)d_in[6];
  const float* nb1 = (const float*)d_in[7];
  const float* nw2 = (const float*)d_in[8];
  const float* nb2 = (const float*)d_in[9];
  const float* gam = (const float*)d_in[10];
  const float* bet = (const float*)d_in[11];

  // ws: eidx 2MB | edist 2MB | hb(bf16 h) 8.4MB (optional). agg lives in d_out.
  const size_t base_need = (size_t)NBATCH * NNODE * KNN * 8;                 // 4 MB
  const size_t hbf_need  = base_need + (size_t)NBATCH * NNODE * HID * 2;     // +8.4 MB
  if (ws_size < base_need) return;
  const bool use_hbf = (ws_size >= hbf_need);

  char* wsp = (char*)d_ws;
  int*   eidx  = (int*)wsp;
  float* edist = (float*)(wsp + (size_t)NBATCH * NNODE * KNN * 4);
  short* hb    = (short*)(wsp + base_need);
  float* agg   = (float*)d_out;

  if (use_hbf) {
    hcvt_kernel<<<dim3(2048), dim3(256), 0, stream>>>(h, hb);
  }
  knn_kernel<<<dim3(1024), dim3(512), 0, stream>>>(pos, eidx, edist);
  if (use_hbf) {
    edge_kernel<true ><<<dim3(256), dim3(512), 0, stream>>>(h, hb, eidx, edist,
                                                            ew1, eb1, ew2, eb2, agg);
    node_kernel<true ><<<dim3(256), dim3(512), 0, stream>>>(h, hb, agg, nw1, nb1,
                                                            nw2, nb2, gam, bet, (float*)d_out);
  } else {
    edge_kernel<false><<<dim3(256), dim3(512), 0, stream>>>(h, hb, eidx, edist,
                                                            ew1, eb1, ew2, eb2, agg);
    node_kernel<false><<<dim3(256), dim3(512), 0, stream>>>(h, hb, agg, nw1, nb1,
                                                            nw2, nb2, gam, bet, (float*)d_out);
  }
}